// Round 8
// baseline (522.818 us; speedup 1.0000x reference)
//
#include <hip/hip_runtime.h>
#include <hip/hip_bf16.h>

#define N_ATOMS 10000
#define N_PAIRS 320000
#define C_ 64
#define NB_ 10

typedef short bf16x8 __attribute__((ext_vector_type(8)));
typedef float f32x4 __attribute__((ext_vector_type(4)));

__device__ __forceinline__ float bf2f(__hip_bfloat16 x) { return __bfloat162float(x); }
__device__ __forceinline__ float ldf(const void* p, int i, int isf32) {
    return isf32 ? ((const float*)p)[i] : bf2f(((const __hip_bfloat16*)p)[i]);
}
__device__ __forceinline__ short f2bs(float x) {
    __hip_bfloat16 h = __float2bfloat16(x);
    return *reinterpret_cast<short*>(&h);
}
__device__ __forceinline__ float bs2f(unsigned short s) {
    return __uint_as_float(((unsigned)s) << 16);
}
// fast tanh: 1 - 2/(exp(2x)+1). err ~1e-6, saturates correctly at +-inf.
__device__ __forceinline__ float tanh_fast(float x) {
    const float e = __expf(2.0f * x);
    return 1.0f - 2.0f * __builtin_amdgcn_rcpf(e + 1.0f);
}

// wbuf f32 offsets
#define W_PPREW1 0
#define W_PPREB1 4096
#define W_PPREW2 4160
#define W_PPREB2 8256
#define W_PIW    8320
#define W_PIB    90240
#define W_IIW    90880
#define W_PPOSTW1 99072
#define W_PPOSTW2 107264
#define W_EQW    111360
#define W_Q1W    115456
#define W_Q1B    123648
#define W_Q2W    123712
#define W_Q2B    131904
#define W_TOTAL  132032

__device__ __forceinline__ int probe_eval(const void* d3)
{
    float sf = 0.f, sb = 0.f;
    const float* f = (const float*)d3;
    const __hip_bfloat16* b = (const __hip_bfloat16*)d3;
    for (int r = 0; r < 4; r++) {
        float x = f[r*3], y = f[r*3+1], z = f[r*3+2];
        float n = x*x + y*y + z*z;
        sf += isfinite(n) ? fabsf(n - 1.f) : 1e30f;
        float xb = bf2f(b[r*3]), yb = bf2f(b[r*3+1]), zb = bf2f(b[r*3+2]);
        float nb = xb*xb + yb*yb + zb*zb;
        sb += isfinite(nb) ? fabsf(nb - 1.f) : 1e30f;
    }
    return (sf < sb) ? 1 : 0;
}

// ---------------- front kernel: probe + hist + v  ||  weight convert ----------------
// blocks [0,1250):    per-pair histogram + v accumulation (dtype probed locally)
// blocks [1250,1766): gather all weights into f32 wbuf (dtype probed locally)
// block 0 also publishes the dtype flag for downstream kernels.
__global__ __launch_bounds__(256) void k_front(
    const void* __restrict__ d3, const void* __restrict__ fc,
    int* __restrict__ flag, const int* __restrict__ ind2,
    int* __restrict__ cnt, float* __restrict__ v,
    const void* s0, const void* s1, const void* s2, const void* s3,
    const void* s4, const void* s5, const void* s6, const void* s7,
    const void* s8, const void* s9, const void* s10, const void* s11,
    const void* s12, const void* s13,
    float* __restrict__ wbuf)
{
    __shared__ int fsh;
    if (threadIdx.x == 0) {
        const int fv = probe_eval(d3);
        fsh = fv;
        if (blockIdx.x == 0) *flag = fv;
    }
    __syncthreads();
    const int isf32 = fsh;
    if (blockIdx.x < 1250) {
        const int p = blockIdx.x * 256 + threadIdx.x;
        if (p >= N_PAIRS) return;
        const int ia = ind2[2 * p];
        atomicAdd(&cnt[ia], 1);
        const float f = ldf(fc, p, isf32);
        #pragma unroll
        for (int x = 0; x < 3; x++)
            atomicAdd(&v[ia * 3 + x], ldf(d3, 3 * p + x, isf32) * f);
        return;
    }
    const int idx = (blockIdx.x - 1250) * 256 + threadIdx.x;
    if (idx >= W_TOTAL) return;
    const int offw[15] = {W_PPREW1, W_PPREB1, W_PPREW2, W_PPREB2, W_PIW, W_PIB,
                          W_IIW, W_PPOSTW1, W_PPOSTW2, W_EQW, W_Q1W, W_Q1B,
                          W_Q2W, W_Q2B, W_TOTAL};
    const void* srcs[14] = {s0,s1,s2,s3,s4,s5,s6,s7,s8,s9,s10,s11,s12,s13};
    int t = 0;
    while (idx >= offw[t + 1]) t++;
    wbuf[idx] = ldf(srcs[t], idx - offw[t], isf32);
}

// ---------------- scan + W1/W2 MFMA-fragment pack ----------------
// block 0: exclusive-scan cnt -> offs, seed cur (skipped when cnt==nullptr).
// blocks [1,17): pack w1F (hi/lo) from wbuf; blocks [17,33): pack w2F.
// Fragment layout mirrors iiW pack (64-col variant): B[k][col] at
//   idx = ((ct*2+s2)*64+lane)*8+j, k = s2*32+(lane>>4)*8+j, col = ct*16+(lane&15).
__global__ __launch_bounds__(256) void k_scan_wfrag(
    const int* __restrict__ cnt, int* __restrict__ offs, int* __restrict__ cur,
    const float* __restrict__ wbuf,
    short* __restrict__ w1Fh, short* __restrict__ w1Fl,
    short* __restrict__ w2Fh, short* __restrict__ w2Fl)
{
    if (blockIdx.x == 0) {
        if (!cnt) return;
        __shared__ int part[256];
        __shared__ int base[257];
        const int t = threadIdx.x;
        const int lo = t * 40, hi = (lo + 40 < N_ATOMS) ? lo + 40 : N_ATOMS;
        int s = 0;
        for (int b = lo; b < hi; b++) s += cnt[b];
        part[t] = s;
        __syncthreads();
        if (t == 0) {
            int run = 0;
            for (int i = 0; i < 256; i++) { base[i] = run; run += part[i]; }
            base[256] = run;
        }
        __syncthreads();
        int run = base[t];
        for (int b = lo; b < hi; b++) { offs[b] = run; cur[b] = run; run += cnt[b]; }
        if (t == 0) offs[N_ATOMS] = base[256];
        return;
    }
    const int b = blockIdx.x - 1;           // 0..31
    const int isW2 = b >= 16;
    const int idx = (b - (isW2 ? 16 : 0)) * 256 + threadIdx.x;   // < 4096
    const int j = idx & 7, lane = (idx >> 3) & 63, s2 = (idx >> 9) & 1, ct = idx >> 10;
    const int k = s2 * 32 + (lane >> 4) * 8 + j;
    const int col = ct * 16 + (lane & 15);
    const float wv = wbuf[(isW2 ? W_PPREW2 : W_PPREW1) + k * 64 + col];
    const short hs = f2bs(wv);
    short* dh = isW2 ? w2Fh : w1Fh;
    short* dl = isW2 ? w2Fl : w1Fl;
    dh[idx] = hs;
    dl[idx] = f2bs(wv - bs2f((unsigned short)hs));
}

// ---------------- pack + MFMA p1_in + scatter (merged launch) ----------------
// blocks [0,352):   pack piWB2 (merged per-cc 32KB hi|lo tiles) and iiWh/iiWl.
// blocks [352,509): p1_in via MFMA, 64 atoms/block (was 2500 scalar-matvec
//                   blocks): tanh(tanh(p1 W1 + b1) W2 + b2), hi/lo split out.
// blocks [509,1759) (fused path only): scatter perm by atom.
__global__ __launch_bounds__(256) void k_prep_scatter(
    const float* __restrict__ wbuf,
    short* __restrict__ piWB2,
    short* __restrict__ iiWh, short* __restrict__ iiWl,
    const void* __restrict__ p1, const int* __restrict__ flagp,
    unsigned short* __restrict__ p1h, unsigned short* __restrict__ p1l,
    const int* __restrict__ ind2, int* __restrict__ cur, int* __restrict__ perm,
    const short* __restrict__ w1Fh, const short* __restrict__ w1Fl,
    const short* __restrict__ w2Fh, const short* __restrict__ w2Fl)
{
    __shared__ float hL[64 * 68];
    if (blockIdx.x >= 509) {
        const int p = (blockIdx.x - 509) * 256 + threadIdx.x;
        if (p < N_PAIRS) {
            const int pos = atomicAdd(&cur[ind2[2 * p]], 1);
            perm[pos] = p;
        }
        return;
    }
    if (blockIdx.x < 352) {
        int idx = blockIdx.x * 256 + threadIdx.x;
        if (idx < 81920) {
            const int j = idx & 7, lane = (idx >> 3) & 63, s = (idx >> 9) & 3, T = idx >> 11;
            const int k = s * 32 + (lane >> 4) * 8 + j;
            const int colp = T * 16 + (lane & 15);
            const int b = colp >> 6, c = colp & 63;
            const float v = wbuf[W_PIW + k * 640 + c * 10 + b];
            const short hs = f2bs(v);
            const int cc = idx >> 13, e = idx & 8191;
            piWB2[cc * 16384 + e] = hs;
            piWB2[cc * 16384 + 8192 + e] = f2bs(v - bs2f((unsigned short)hs));
            return;
        }
        idx -= 81920;
        if (idx < 8192) {
            const int j = idx & 7, lane = (idx >> 3) & 63, s2 = (idx >> 9) & 1, ct = idx >> 10;
            const int k = s2 * 32 + (lane >> 4) * 8 + j;
            const int col = ct * 16 + (lane & 15);
            const float wv = wbuf[W_IIW + k * 128 + col];
            const short hs = f2bs(wv);
            iiWh[idx] = hs;
            iiWl[idx] = f2bs(wv - bs2f((unsigned short)hs));
        }
        return;
    }
    // ---- p1_in via MFMA (proven fragment patterns from the pairs kernel) ----
    const int isf32 = *flagp;
    const int t = threadIdx.x;
    const int lane = t & 63, w = t >> 6, lc = lane & 15, quad = lane >> 4;
    const int B0 = (blockIdx.x - 352) * 64;

    // A-frags from p1 rows with on-the-fly hi/lo split (row = B0+w*16+lc)
    bf16x8 xh[2], xl[2];
    {
        const int a = B0 + w * 16 + lc;
        const int ar = (a < N_ATOMS) ? a : N_ATOMS - 1;   // clamp OOB loads
        #pragma unroll
        for (int s2 = 0; s2 < 2; s2++) {
            const int base = ar * 64 + s2 * 32 + quad * 8;
            #pragma unroll
            for (int j = 0; j < 8; j++) {
                const float x = ldf(p1, base + j, isf32);
                const short hs = f2bs(x);
                xh[s2][j] = hs;
                xl[s2][j] = f2bs(x - bs2f((unsigned short)hs));
            }
        }
    }
    // GEMM A: h = tanh(X W1 + b1) -> hL (stride-68 transform, preL pattern)
    #pragma unroll
    for (int tt = 0; tt < 4; tt++) {
        f32x4 acc = {0.f, 0.f, 0.f, 0.f};
        #pragma unroll
        for (int s2 = 0; s2 < 2; s2++) {
            bf16x8 bh = *(const bf16x8*)&w1Fh[((tt * 2 + s2) * 64 + lane) * 8];
            bf16x8 bl = *(const bf16x8*)&w1Fl[((tt * 2 + s2) * 64 + lane) * 8];
            acc = __builtin_amdgcn_mfma_f32_16x16x32_bf16(xh[s2], bh, acc, 0, 0, 0);
            acc = __builtin_amdgcn_mfma_f32_16x16x32_bf16(xl[s2], bh, acc, 0, 0, 0);
            acc = __builtin_amdgcn_mfma_f32_16x16x32_bf16(xh[s2], bl, acc, 0, 0, 0);
        }
        const int c = tt * 16 + lc;
        const float b1v = wbuf[W_PPREB1 + c];
        #pragma unroll
        for (int r = 0; r < 4; r++) {
            const int m = w * 16 + quad * 4 + r;
            hL[m * 68 + c] = tanh_fast(acc[r] + b1v);
        }
    }
    __syncthreads();
    // rebuild A-frags from hL
    bf16x8 hh[2], hl[2];
    {
        const int row = w * 16 + lc;
        #pragma unroll
        for (int s2 = 0; s2 < 2; s2++) {
            const float* pr = &hL[row * 68 + s2 * 32 + quad * 8];
            #pragma unroll
            for (int j = 0; j < 8; j++) {
                const float x = pr[j];
                const short hs = f2bs(x);
                hh[s2][j] = hs;
                hl[s2][j] = f2bs(x - bs2f((unsigned short)hs));
            }
        }
    }
    // GEMM B: p1_in = tanh(h W2 + b2) -> hi/lo split to p1h/p1l
    #pragma unroll
    for (int tt = 0; tt < 4; tt++) {
        f32x4 acc = {0.f, 0.f, 0.f, 0.f};
        #pragma unroll
        for (int s2 = 0; s2 < 2; s2++) {
            bf16x8 bh = *(const bf16x8*)&w2Fh[((tt * 2 + s2) * 64 + lane) * 8];
            bf16x8 bl = *(const bf16x8*)&w2Fl[((tt * 2 + s2) * 64 + lane) * 8];
            acc = __builtin_amdgcn_mfma_f32_16x16x32_bf16(hh[s2], bh, acc, 0, 0, 0);
            acc = __builtin_amdgcn_mfma_f32_16x16x32_bf16(hl[s2], bh, acc, 0, 0, 0);
            acc = __builtin_amdgcn_mfma_f32_16x16x32_bf16(hh[s2], bl, acc, 0, 0, 0);
        }
        const int c = tt * 16 + lc;
        const float b2v = wbuf[W_PPREB2 + c];
        #pragma unroll
        for (int r = 0; r < 4; r++) {
            const int m = w * 16 + quad * 4 + r;
            const int a = B0 + m;
            if (a < N_ATOMS) {
                const float f = tanh_fast(acc[r] + b2v);
                const short hs = f2bs(f);
                p1h[a * 64 + c] = (unsigned short)hs;
                p1l[a * 64 + c] = (unsigned short)f2bs(f - bs2f((unsigned short)hs));
            }
        }
    }
}

// ---------------- fused per-pair MFMA + sorted segment-reduce ----------------
// v8 = v7 unchanged (proven 268us): pure __syncthreads, transient-reg staging,
// perm-indirect input reads, XCD-aware block swizzle, wave-split reduce.
__global__ __launch_bounds__(256) void k_pairs_fused(
    const int* __restrict__ ind2, const void* __restrict__ basis,
    const void* __restrict__ d3, const void* __restrict__ fc,
    const int* __restrict__ perm,
    const void* __restrict__ p3,
    const float* __restrict__ wbuf,
    const short* __restrict__ piWB2,
    const short* __restrict__ iiWh, const short* __restrict__ iiWl,
    const unsigned short* __restrict__ p1h, const unsigned short* __restrict__ p1l,
    const int* __restrict__ flagp, const float* __restrict__ vglob,
    float* __restrict__ p1scat, float* __restrict__ p3acc)
{
    // LDS overlay plan (SH = 33280 B; total block LDS ~40.9KB -> 4 blocks/CU):
    //   [0,32768)  Bbuf (merged hi|lo stage)      -- GEMM1 only
    //   [0,17408)  preL (GEMM1->GEMM2 transform)  -- after GEMM1 barrier
    //   [0,33280)  ipL  64 pairs x 130 f32        -- after ah2 barrier
    __shared__ __align__(16) char SH[33280];
    __shared__ float basisL[640];
    __shared__ float biasT[640];
    __shared__ int sIL[65], sJL[64];
    __shared__ float d3L[64][3], t3L[64][3], tbL[64];

    unsigned short* Bbuf = (unsigned short*)SH;
    float* preL = (float*)SH;
    float* ipL  = (float*)SH;

    const int t = threadIdx.x;
    // XCD swizzle: 5000 blocks = 8 XCDs x 625; block b sits on XCD b%8; give
    // each XCD a contiguous chunk of sorted-pair space.
    const int bid = blockIdx.x;
    const int P0 = ((bid & 7) * 625 + (bid >> 3)) * 64;
    const int isf32 = *flagp;
    const int lane = t & 63;
    const int w = t >> 6;
    const int lc = lane & 15;
    const int quad = lane >> 4;

    if (t < 64) {
        const int p = perm[P0 + t];
        int2 ij = ((const int2*)ind2)[p];
        sIL[t] = ij.x; sJL[t] = ij.y;
        const float vi0 = vglob[ij.x * 3 + 0], vi1 = vglob[ij.x * 3 + 1], vi2 = vglob[ij.x * 3 + 2];
        const float d0 = ldf(d3, 3 * p + 0, isf32);
        const float d1 = ldf(d3, 3 * p + 1, isf32);
        const float d2 = ldf(d3, 3 * p + 2, isf32);
        d3L[t][0] = d0; d3L[t][1] = d1; d3L[t][2] = d2;
        const float proj = vi0 * d0 + vi1 * d1 + vi2 * d2;
        const float w0 = vi0 - proj * d0, w1 = vi1 - proj * d1, w2v = vi2 - proj * d2;
        const float w2 = w0 * w0 + w1 * w1 + w2v * w2v;
        const float g = w2 / (w2 + 1e-4f);
        const float rs = rsqrtf(w2 + 1e-6f);
        t3L[t][0] = w0 * rs * g; t3L[t][1] = w1 * rs * g; t3L[t][2] = w2v * rs * g;
        const float f = ldf(fc, p, isf32);
        tbL[t] = g * f * f;
    }
    if (t == 64) sIL[64] = -1;   // sentinel: forces segment flush at m=63
    // basis gather through perm (40B rows at random offsets; hides under setup)
    for (int e = t; e < 640; e += 256) {
        const int pm = e / 10, col = e - pm * 10;
        basisL[e] = ldf(basis, perm[P0 + pm] * 10 + col, isf32);
    }
    // bias transposed into LDS: biasT[cc*64+c]
    for (int e = t; e < 640; e += 256) biasT[e] = wbuf[W_PIB + (e & 63) * 10 + (e >> 6)];
    __syncthreads();

    // A-frags: row m = lc (pair w*16+lc), k = s*32 + quad*8 + j
    bf16x8 ah[4], al[4];
    {
        const int ia = sIL[w * 16 + lc];
        const int ja = sJL[w * 16 + lc];
        #pragma unroll
        for (int s = 0; s < 4; s++) {
            const int atom = (s < 2) ? ia : ja;
            const int off = atom * 64 + (s & 1) * 32 + quad * 8;
            ah[s] = *(const bf16x8*)(p1h + off);
            al[s] = *(const bf16x8*)(p1l + off);
        }
    }

    // GEMM1: acc = Xh*Wh + Xl*Wh + Xh*Wl  (drop lo*lo)
    float sr[4][4];
    #pragma unroll
    for (int r = 0; r < 4; r++)
        #pragma unroll
        for (int ph = 0; ph < 4; ph++) sr[r][ph] = 0.f;

    for (int cc = 0; cc < 10; cc++) {
        if (cc) __syncthreads();          // prev tile reads done
        {   // stage merged 32KB hi|lo tile (transient regs; no spill)
            const uint4* gsrc = (const uint4*)(piWB2 + cc * 16384);
            uint4* ldst = (uint4*)Bbuf;
            #pragma unroll
            for (int r = 0; r < 8; r++) ldst[r * 256 + t] = gsrc[r * 256 + t];
        }
        __syncthreads();                  // tile staged
        #pragma unroll
        for (int tt = 0; tt < 4; tt++) {
            f32x4 acc = {0.f, 0.f, 0.f, 0.f};
            #pragma unroll
            for (int s = 0; s < 4; s++) {
                const int e = ((tt * 4 + s) * 64 + lane) * 8;
                bf16x8 bh = *(const bf16x8*)&Bbuf[e];
                bf16x8 bl = *(const bf16x8*)&Bbuf[8192 + e];
                acc = __builtin_amdgcn_mfma_f32_16x16x32_bf16(ah[s], bh, acc, 0, 0, 0);
                acc = __builtin_amdgcn_mfma_f32_16x16x32_bf16(al[s], bh, acc, 0, 0, 0);
                acc = __builtin_amdgcn_mfma_f32_16x16x32_bf16(ah[s], bl, acc, 0, 0, 0);
            }
            const float bias = biasT[cc * 64 + tt * 16 + lc];
            #pragma unroll
            for (int r = 0; r < 4; r++) {
                const int m = w * 16 + quad * 4 + r;
                const float h = tanh_fast(acc[r] + bias);
                sr[r][tt] += h * basisL[m * 10 + cc];
            }
        }
    }
    __syncthreads();   // last tile reads done before preL overlay

    // pre -> LDS (C-layout to A-layout transform)
    #pragma unroll
    for (int r = 0; r < 4; r++)
        #pragma unroll
        for (int ph = 0; ph < 4; ph++)
            preL[(w * 16 + quad * 4 + r) * 68 + ph * 16 + lc] = sr[r][ph];
    __syncthreads();

    bf16x8 ah2[2], al2[2];
    {
        const int row = w * 16 + lc;
        #pragma unroll
        for (int s2 = 0; s2 < 2; s2++) {
            const float* pr2 = &preL[row * 68 + s2 * 32 + quad * 8];
            #pragma unroll
            for (int j = 0; j < 8; j++) {
                const float x = pr2[j];
                const short hs = f2bs(x);
                ah2[s2][j] = hs;
                al2[s2][j] = f2bs(x - bs2f((unsigned short)hs));
            }
        }
    }
    __syncthreads();   // preL reads done before ipL overlay writes

    // Phase-B chunk-0 gather issued HERE: overlaps GEMM2's MFMAs below and
    // completes at the next __syncthreads' vmcnt drain.
    float pv0[16];
    if (t < 192) {
        #pragma unroll
        for (int u = 0; u < 16; u++) pv0[u] = ldf(p3, sJL[u] * 192 + t, isf32);
    }

    // GEMM2: i_pair -> LDS (stride 130 keeps banks at 2-way = free)
    #pragma unroll
    for (int ct = 0; ct < 8; ct++) {
        f32x4 acc = {0.f, 0.f, 0.f, 0.f};
        #pragma unroll
        for (int s2 = 0; s2 < 2; s2++) {
            bf16x8 bh = *(const bf16x8*)&iiWh[((ct * 2 + s2) * 64 + lane) * 8];
            bf16x8 bl = *(const bf16x8*)&iiWl[((ct * 2 + s2) * 64 + lane) * 8];
            acc = __builtin_amdgcn_mfma_f32_16x16x32_bf16(ah2[s2], bh, acc, 0, 0, 0);
            acc = __builtin_amdgcn_mfma_f32_16x16x32_bf16(al2[s2], bh, acc, 0, 0, 0);
            acc = __builtin_amdgcn_mfma_f32_16x16x32_bf16(ah2[s2], bl, acc, 0, 0, 0);
        }
        const int ch = ct * 16 + lc;
        #pragma unroll
        for (int r = 0; r < 4; r++) {
            const int m = w * 16 + quad * 4 + r;
            ipL[m * 130 + ch] = tanh_fast(acc[r]);
        }
    }
    __syncthreads();   // ipL published (pv0 also complete here)

    if (t < 192) {
        // Phase B (waves 0-2): p3 message segment-sum, one x-component per wave
        const int x = t >> 6, cc2 = t & 63;
        float acc = 0.f;
        #pragma unroll
        for (int blk = 0; blk < 4; blk++) {
            float pv[16];
            if (blk == 0) {
                #pragma unroll
                for (int u = 0; u < 16; u++) pv[u] = pv0[u];
            } else {
                #pragma unroll
                for (int u = 0; u < 16; u++)
                    pv[u] = ldf(p3, sJL[blk * 16 + u] * 192 + t, isf32);
            }
            #pragma unroll
            for (int u = 0; u < 16; u++) {
                const int m = blk * 16 + u;
                const float ipb = ipL[m * 130 + 64 + cc2];
                acc += (pv[u] + d3L[m][x]) * ipb + t3L[m][x] * (ipb * tbL[m]);
                if (sIL[m + 1] != sIL[m]) {
                    atomicAdd(&p3acc[(size_t)sIL[m] * 192 + t], acc);
                    acc = 0.f;
                }
            }
        }
    } else {
        // Phase A (wave 3): p1scat segment-sum, 2 channels per thread
        const int ch0 = t - 192;
        float a0 = 0.f, a1 = 0.f;
        #pragma unroll 8
        for (int m = 0; m < 64; m++) {
            a0 += ipL[m * 130 + ch0];
            a1 += ipL[m * 130 + 64 + ch0];
            if (sIL[m + 1] != sIL[m]) {
                const size_t base = (size_t)sIL[m] * 128;
                atomicAdd(&p1scat[base + ch0], a0);
                atomicAdd(&p1scat[base + 64 + ch0], a1);
                a0 = 0.f; a1 = 0.f;
            }
        }
    }
}

// ---------------- legacy atomic-path per-pair kernel (fallback) ----------------
__global__ __launch_bounds__(256) void k_pairs_atomic(
    const int* __restrict__ ind2, const void* __restrict__ basis,
    const void* __restrict__ d3, const void* __restrict__ fc,
    const void* __restrict__ p3,
    const float* __restrict__ wbuf,
    const short* __restrict__ piWB2,
    const short* __restrict__ iiWh, const short* __restrict__ iiWl,
    const unsigned short* __restrict__ p1h, const unsigned short* __restrict__ p1l,
    const int* __restrict__ flagp, const float* __restrict__ vglob,
    float* __restrict__ outA, float* __restrict__ outB)
{
    __shared__ __align__(16) unsigned short Bbuf[8192];
    __shared__ __align__(16) char SH[17408];
    __shared__ float basisL[640];
    __shared__ int sIL[64], sJL[64];
    __shared__ float d3L[64][3], t3L[64][3], tbL[64];

    float* preL = (float*)SH;
    float* i1bL = (float*)SH;

    const int t = threadIdx.x;
    const int P0 = blockIdx.x * 64;
    const int isf32 = *flagp;
    const int lane = t & 63;
    const int w = t >> 6;
    const int lc = lane & 15;
    const int quad = lane >> 4;

    if (t < 64) {
        int2 ij = ((const int2*)ind2)[P0 + t];
        sIL[t] = ij.x; sJL[t] = ij.y;
    }
    for (int e = t; e < 640; e += 256) basisL[e] = ldf(basis, P0 * 10 + e, isf32);
    __syncthreads();

    bf16x8 ah[4], al[4];
    {
        const int ia = sIL[w * 16 + lc];
        const int ja = sJL[w * 16 + lc];
        #pragma unroll
        for (int s = 0; s < 4; s++) {
            const int atom = (s < 2) ? ia : ja;
            const int off = atom * 64 + (s & 1) * 32 + quad * 8;
            ah[s] = *(const bf16x8*)(p1h + off);
            al[s] = *(const bf16x8*)(p1l + off);
        }
    }

    float sr[4][4];
    #pragma unroll
    for (int r = 0; r < 4; r++)
        #pragma unroll
        for (int ph = 0; ph < 4; ph++) sr[r][ph] = 0.f;

    for (int cc = 0; cc < 10; cc++) {
        f32x4 acc[4];
        #pragma unroll
        for (int tt = 0; tt < 4; tt++) acc[tt] = (f32x4){0.f, 0.f, 0.f, 0.f};

        __syncthreads();
        {
            const uint4* gsrc = (const uint4*)(piWB2 + cc * 16384);
            uint4* ldst = (uint4*)Bbuf;
            #pragma unroll
            for (int r = 0; r < 4; r++) ldst[r * 256 + t] = gsrc[r * 256 + t];
        }
        __syncthreads();
        #pragma unroll
        for (int tt = 0; tt < 4; tt++) {
            #pragma unroll
            for (int s = 0; s < 4; s++) {
                bf16x8 bfr = *(const bf16x8*)&Bbuf[((tt * 4 + s) * 64 + lane) * 8];
                acc[tt] = __builtin_amdgcn_mfma_f32_16x16x32_bf16(ah[s], bfr, acc[tt], 0, 0, 0);
                acc[tt] = __builtin_amdgcn_mfma_f32_16x16x32_bf16(al[s], bfr, acc[tt], 0, 0, 0);
            }
        }
        __syncthreads();
        {
            const uint4* gsrc = (const uint4*)(piWB2 + cc * 16384 + 8192);
            uint4* ldst = (uint4*)Bbuf;
            #pragma unroll
            for (int r = 0; r < 4; r++) ldst[r * 256 + t] = gsrc[r * 256 + t];
        }
        __syncthreads();
        #pragma unroll
        for (int tt = 0; tt < 4; tt++) {
            #pragma unroll
            for (int s = 0; s < 4; s++) {
                bf16x8 bfr = *(const bf16x8*)&Bbuf[((tt * 4 + s) * 64 + lane) * 8];
                acc[tt] = __builtin_amdgcn_mfma_f32_16x16x32_bf16(ah[s], bfr, acc[tt], 0, 0, 0);
            }
            const int c = tt * 16 + lc;
            const float bias = wbuf[W_PIB + c * 10 + cc];
            #pragma unroll
            for (int r = 0; r < 4; r++) {
                const int m = w * 16 + quad * 4 + r;
                const float h = tanh_fast(acc[tt][r] + bias);
                sr[r][tt] += h * basisL[m * 10 + cc];
            }
        }
    }

    #pragma unroll
    for (int r = 0; r < 4; r++)
        #pragma unroll
        for (int ph = 0; ph < 4; ph++)
            preL[(w * 16 + quad * 4 + r) * 68 + ph * 16 + lc] = sr[r][ph];
    __syncthreads();

    bf16x8 ah2[2], al2[2];
    {
        const int row = w * 16 + lc;
        #pragma unroll
        for (int s2 = 0; s2 < 2; s2++) {
            const float* pr2 = &preL[row * 68 + s2 * 32 + quad * 8];
            #pragma unroll
            for (int j = 0; j < 8; j++) {
                const float x = pr2[j];
                const short hs = f2bs(x);
                ah2[s2][j] = hs;
                al2[s2][j] = f2bs(x - bs2f((unsigned short)hs));
            }
        }
    }
    __syncthreads();

    #pragma unroll
    for (int ct = 0; ct < 8; ct++) {
        f32x4 acc = {0.f, 0.f, 0.f, 0.f};
        #pragma unroll
        for (int s2 = 0; s2 < 2; s2++) {
            bf16x8 bh = *(const bf16x8*)&iiWh[((ct * 2 + s2) * 64 + lane) * 8];
            bf16x8 bl = *(const bf16x8*)&iiWl[((ct * 2 + s2) * 64 + lane) * 8];
            acc = __builtin_amdgcn_mfma_f32_16x16x32_bf16(ah2[s2], bh, acc, 0, 0, 0);
            acc = __builtin_amdgcn_mfma_f32_16x16x32_bf16(al2[s2], bh, acc, 0, 0, 0);
            acc = __builtin_amdgcn_mfma_f32_16x16x32_bf16(ah2[s2], bl, acc, 0, 0, 0);
        }
        const int ch = ct * 16 + lc;
        #pragma unroll
        for (int r = 0; r < 4; r++) {
            const int m = w * 16 + quad * 4 + r;
            const float val = tanh_fast(acc[r]);
            atomicAdd(&outA[(size_t)sIL[m] * 128 + ch], val);
            if (ch >= 64) i1bL[m * 64 + (ch - 64)] = val;
        }
    }

    __syncthreads();
    if (t < 64) {
        const int m = t;
        const int ia = sIL[m];
        const float vi0 = vglob[ia * 3 + 0], vi1 = vglob[ia * 3 + 1], vi2 = vglob[ia * 3 + 2];
        const float d0 = ldf(d3, (P0 + m) * 3 + 0, isf32);
        const float d1 = ldf(d3, (P0 + m) * 3 + 1, isf32);
        const float d2 = ldf(d3, (P0 + m) * 3 + 2, isf32);
        d3L[m][0] = d0; d3L[m][1] = d1; d3L[m][2] = d2;
        const float proj = vi0 * d0 + vi1 * d1 + vi2 * d2;
        const float w0 = vi0 - proj * d0, w1 = vi1 - proj * d1, w2v = vi2 - proj * d2;
        const float w2 = w0 * w0 + w1 * w1 + w2v * w2v;
        const float g = w2 / (w2 + 1e-4f);
        const float rs = rsqrtf(w2 + 1e-6f);
        t3L[m][0] = w0 * rs * g; t3L[m][1] = w1 * rs * g; t3L[m][2] = w2v * rs * g;
        const float f = ldf(fc, P0 + m, isf32);
        tbL[m] = g * f * f;
    }
    __syncthreads();
    const int c = lane;
    #pragma unroll 4
    for (int mm = 0; mm < 16; mm++) {
        const int m = w * 16 + mm;
        const float bv = i1bL[m * 64 + c];
        const float coef = bv * tbL[m];
        #pragma unroll
        for (int x = 0; x < 3; x++) {
            const float p3v = ldf(p3, sJL[m] * 192 + x * 64 + c, isf32);
            atomicAdd(&outB[(size_t)sIL[m] * 192 + x * 64 + c],
                      p3v * bv + d3L[m][x] * bv + t3L[m][x] * coef);
        }
    }
}

// ---------------- per-atom epilogue ----------------
__global__ __launch_bounds__(256) void k_final(
    const float* __restrict__ p1scat, const float* __restrict__ p3acc,
    const float* __restrict__ wbuf, const int* __restrict__ flagp,
    void* __restrict__ out)
{
    const float* ppW1 = wbuf + W_PPOSTW1;
    const float* ppW2 = wbuf + W_PPOSTW2;
    const float* eqW  = wbuf + W_EQW;
    const float* q1W  = wbuf + W_Q1W;
    const float* q1b  = wbuf + W_Q1B;
    const float* q2W  = wbuf + W_Q2W;
    const float* q2b  = wbuf + W_Q2B;
    const int isf32 = *flagp;

    __shared__ float s1[4][128];
    __shared__ float hA[4][64];
    __shared__ float cat[4][128];
    __shared__ float p3a[4][192];
    const int t = threadIdx.x;
    const int slot = t >> 6, c = t & 63;
    const int atom = blockIdx.x * 4 + slot;

    s1[slot][c]        = p1scat[atom * 128 + c];
    s1[slot][64 + c]   = p1scat[atom * 128 + 64 + c];
    p3a[slot][c]       = p3acc[atom * 192 + c];
    p3a[slot][64 + c]  = p3acc[atom * 192 + 64 + c];
    p3a[slot][128 + c] = p3acc[atom * 192 + 128 + c];
    __syncthreads();

    float acc = 0.f;
    for (int k = 0; k < 128; k++) acc += s1[slot][k] * ppW1[k * 64 + c];
    hA[slot][c] = tanh_fast(acc);
    __syncthreads();
    acc = 0.f;
    for (int k = 0; k < 64; k++) acc += hA[slot][k] * ppW2[k * 64 + c];
    cat[slot][c] = tanh_fast(acc);

    float pn[3];
    float dot = 0.f;
    #pragma unroll
    for (int x = 0; x < 3; x++) {
        float a = 0.f;
        for (int k = 0; k < 64; k++) a += p3a[slot][x * 64 + k] * eqW[k * 64 + c];
        pn[x] = a;
        dot += a * a;
    }
    cat[slot][64 + c] = dot;
    __syncthreads();

    acc = q1b[c];
    for (int k = 0; k < 128; k++) acc += cat[slot][k] * q1W[k * 64 + c];
    __syncthreads();
    hA[slot][c] = tanh_fast(acc);
    __syncthreads();

    float g1acc = q2b[c], g3acc = q2b[c + 64];
    for (int k = 0; k < 64; k++) {
        const float hv = hA[slot][k];
        g1acc += hv * q2W[k * 128 + c];
        g3acc += hv * q2W[k * 128 + c + 64];
    }
    const float g1 = tanh_fast(g1acc);
    const float g3 = tanh_fast(g3acc);
    if (isf32) {
        float* p1o = (float*)out;
        float* p3o = p1o + 640000;
        p1o[atom * 64 + c] = g1;
        #pragma unroll
        for (int x = 0; x < 3; x++) p3o[atom * 192 + x * 64 + c] = pn[x] * g3;
    } else {
        __hip_bfloat16* p1o = (__hip_bfloat16*)out;
        __hip_bfloat16* p3o = p1o + 640000;
        p1o[atom * 64 + c] = __float2bfloat16(g1);
        #pragma unroll
        for (int x = 0; x < 3; x++) p3o[atom * 192 + x * 64 + c] = __float2bfloat16(pn[x] * g3);
    }
}

extern "C" void kernel_launch(void* const* d_in, const int* in_sizes, int n_in,
                              void* d_out, int out_size, void* d_ws, size_t ws_size,
                              hipStream_t stream)
{
    const int* ind2 = (const int*)d_in[0];
    const void* p1    = d_in[1];
    const void* p3    = d_in[2];
    const void* basis = d_in[3];
    const void* d3    = d_in[4];
    const void* fc    = d_in[5];

    char* W = (char*)d_ws;
    float* wbuf  = (float*)(W + 0);                       // 528128 B
    short* piWB2 = (short*)(W + 528128);                  // 655360 B -> 1183488
    short* iiWh  = (short*)(W + 1183488);                 // 16384 B -> 1199872
    short* iiWl  = (short*)(W + 1199872);                 // 16384 B -> 1216256
    unsigned short* p1h = (unsigned short*)(W + 1216256); // 1280000 B -> 2496256
    unsigned short* p1l = (unsigned short*)(W + 2496256); // 1280000 B -> 3776256
    int* flag = (int*)(W + 3776256);                      // 64 B -> 3776320
    short* w1Fh = (short*)(W + 3776320);                  // 8192 B -> 3784512
    short* w1Fl = (short*)(W + 3784512);                  // 8192 B -> 3792704
    short* w2Fh = (short*)(W + 3792704);                  // 8192 B -> 3800896
    short* w2Fl = (short*)(W + 3800896);                  // 8192 B -> 3809088

    const int fused = (ws_size >= 18129216ULL) ? 1 : 0;

    if (fused) {
        int* offs     = (int*)(W + 3809088);      // 40016 B -> pad 3849216
        int* cur      = (int*)(W + 3849216);      // 40000 B -> 3889216
        int* perm     = (int*)(W + 3889216);      // 1280000 B -> 5169216
        int* cnt      = (int*)(W + 5169216);      // 40000 B -> 5209216
        float* v      = (float*)(W + 5209216);    // 120000 B -> 5329216
        float* p1scat = (float*)(W + 5329216);    // 5120000 B -> 10449216
        float* p3acc  = (float*)(W + 10449216);   // 7680000 B -> ends 18129216

        // one contiguous zero: cnt + v + p1scat + p3acc
        hipMemsetAsync(cnt, 0, 40000 + 120000 + 5120000 + 7680000, stream);
        k_front<<<1766, 256, 0, stream>>>(d3, fc, flag, ind2, cnt, v,
            d_in[6], d_in[7], d_in[8], d_in[9], d_in[10], d_in[11], d_in[12],
            d_in[13], d_in[14], d_in[15], d_in[16], d_in[17], d_in[18], d_in[19],
            wbuf);
        k_scan_wfrag<<<33, 256, 0, stream>>>(cnt, offs, cur, wbuf,
                                             w1Fh, w1Fl, w2Fh, w2Fl);
        k_prep_scatter<<<1759, 256, 0, stream>>>(wbuf, piWB2, iiWh, iiWl, p1, flag,
                                                 p1h, p1l, ind2, cur, perm,
                                                 w1Fh, w1Fl, w2Fh, w2Fl);
        k_pairs_fused<<<5000, 256, 0, stream>>>(ind2, basis, d3, fc, perm, p3,
                                                wbuf, piWB2, iiWh, iiWl,
                                                p1h, p1l, flag, v, p1scat, p3acc);
        k_final<<<2500, 256, 0, stream>>>(p1scat, p3acc, wbuf, flag, d_out);
    } else {
        int* cnt      = (int*)(W + 3809088);      // 40000 B -> 3849088
        float* v      = (float*)(W + 3849088);    // 120000 B -> 3969088
        float* p1scat = (float*)(W + 3969088);    // 5120000 B -> 9089088
        float* p3acc  = (float*)(W + 9089088);    // 7680000 B -> ends 16769088

        hipMemsetAsync(cnt, 0, 40000 + 120000 + 5120000 + 7680000, stream);
        k_front<<<1766, 256, 0, stream>>>(d3, fc, flag, ind2, cnt, v,
            d_in[6], d_in[7], d_in[8], d_in[9], d_in[10], d_in[11], d_in[12],
            d_in[13], d_in[14], d_in[15], d_in[16], d_in[17], d_in[18], d_in[19],
            wbuf);
        k_scan_wfrag<<<33, 256, 0, stream>>>(nullptr, nullptr, nullptr, wbuf,
                                             w1Fh, w1Fl, w2Fh, w2Fl);
        k_prep_scatter<<<509, 256, 0, stream>>>(wbuf, piWB2, iiWh, iiWl, p1, flag,
                                                p1h, p1l, nullptr, nullptr, nullptr,
                                                w1Fh, w1Fl, w2Fh, w2Fl);
        k_pairs_atomic<<<5000, 256, 0, stream>>>(ind2, basis, d3, fc, p3,
                                                 wbuf, piWB2, iiWh, iiWl,
                                                 p1h, p1l, flag, v,
                                                 p1scat, p3acc);
        k_final<<<2500, 256, 0, stream>>>(p1scat, p3acc, wbuf, flag, d_out);
    }
}

// Round 9
// 484.861 us; speedup vs baseline: 1.0783x; 1.0783x over previous
//
#include <hip/hip_runtime.h>
#include <hip/hip_bf16.h>

#define N_ATOMS 10000
#define N_PAIRS 320000
#define C_ 64
#define NB_ 10

typedef short bf16x8 __attribute__((ext_vector_type(8)));
typedef float f32x4 __attribute__((ext_vector_type(4)));

__device__ __forceinline__ float bf2f(__hip_bfloat16 x) { return __bfloat162float(x); }
__device__ __forceinline__ float ldf(const void* p, int i, int isf32) {
    return isf32 ? ((const float*)p)[i] : bf2f(((const __hip_bfloat16*)p)[i]);
}
__device__ __forceinline__ short f2bs(float x) {
    __hip_bfloat16 h = __float2bfloat16(x);
    return *reinterpret_cast<short*>(&h);
}
__device__ __forceinline__ float bs2f(unsigned short s) {
    return __uint_as_float(((unsigned)s) << 16);
}
// fast tanh: 1 - 2/(exp(2x)+1). err ~1e-6, saturates correctly at +-inf.
__device__ __forceinline__ float tanh_fast(float x) {
    const float e = __expf(2.0f * x);
    return 1.0f - 2.0f * __builtin_amdgcn_rcpf(e + 1.0f);
}

// wbuf f32 offsets
#define W_PPREW1 0
#define W_PPREB1 4096
#define W_PPREW2 4160
#define W_PPREB2 8256
#define W_PIW    8320
#define W_PIB    90240
#define W_IIW    90880
#define W_PPOSTW1 99072
#define W_PPOSTW2 107264
#define W_EQW    111360
#define W_Q1W    115456
#define W_Q1B    123648
#define W_Q2W    123712
#define W_Q2B    131904
#define W_TOTAL  132032

__device__ __forceinline__ int probe_eval(const void* d3)
{
    float sf = 0.f, sb = 0.f;
    const float* f = (const float*)d3;
    const __hip_bfloat16* b = (const __hip_bfloat16*)d3;
    for (int r = 0; r < 4; r++) {
        float x = f[r*3], y = f[r*3+1], z = f[r*3+2];
        float n = x*x + y*y + z*z;
        sf += isfinite(n) ? fabsf(n - 1.f) : 1e30f;
        float xb = bf2f(b[r*3]), yb = bf2f(b[r*3+1]), zb = bf2f(b[r*3+2]);
        float nb = xb*xb + yb*yb + zb*zb;
        sb += isfinite(nb) ? fabsf(nb - 1.f) : 1e30f;
    }
    return (sf < sb) ? 1 : 0;
}

// ---------------- front kernel: probe + hist + v  ||  weight convert ----------------
__global__ __launch_bounds__(256) void k_front(
    const void* __restrict__ d3, const void* __restrict__ fc,
    int* __restrict__ flag, const int* __restrict__ ind2,
    int* __restrict__ cnt, float* __restrict__ v,
    const void* s0, const void* s1, const void* s2, const void* s3,
    const void* s4, const void* s5, const void* s6, const void* s7,
    const void* s8, const void* s9, const void* s10, const void* s11,
    const void* s12, const void* s13,
    float* __restrict__ wbuf)
{
    __shared__ int fsh;
    if (threadIdx.x == 0) {
        const int fv = probe_eval(d3);
        fsh = fv;
        if (blockIdx.x == 0) *flag = fv;
    }
    __syncthreads();
    const int isf32 = fsh;
    if (blockIdx.x < 1250) {
        const int p = blockIdx.x * 256 + threadIdx.x;
        if (p >= N_PAIRS) return;
        const int ia = ind2[2 * p];
        atomicAdd(&cnt[ia], 1);
        const float f = ldf(fc, p, isf32);
        #pragma unroll
        for (int x = 0; x < 3; x++)
            atomicAdd(&v[ia * 3 + x], ldf(d3, 3 * p + x, isf32) * f);
        return;
    }
    const int idx = (blockIdx.x - 1250) * 256 + threadIdx.x;
    if (idx >= W_TOTAL) return;
    const int offw[15] = {W_PPREW1, W_PPREB1, W_PPREW2, W_PPREB2, W_PIW, W_PIB,
                          W_IIW, W_PPOSTW1, W_PPOSTW2, W_EQW, W_Q1W, W_Q1B,
                          W_Q2W, W_Q2B, W_TOTAL};
    const void* srcs[14] = {s0,s1,s2,s3,s4,s5,s6,s7,s8,s9,s10,s11,s12,s13};
    int t = 0;
    while (idx >= offw[t + 1]) t++;
    wbuf[idx] = ldf(srcs[t], idx - offw[t], isf32);
}

// ---------------- scan + all weight MFMA-fragment packs ----------------
// block 0: scan (fused path). blocks [1,33): w1F/w2F (pp_pre).
// blocks [33,65): pA = ppW1 (K=128 role). [65,81): pB = ppW2 (K=64 role).
// [81,97): pE = eqW. [97,129): pQ1 = q1W (K=128). [129,161): pQ2 = q2W (N=128 role).
__global__ __launch_bounds__(256) void k_scan_wfrag(
    const int* __restrict__ cnt, int* __restrict__ offs, int* __restrict__ cur,
    const float* __restrict__ wbuf,
    short* __restrict__ w1Fh, short* __restrict__ w1Fl,
    short* __restrict__ w2Fh, short* __restrict__ w2Fl,
    short* __restrict__ pAh, short* __restrict__ pAl,
    short* __restrict__ pBh, short* __restrict__ pBl,
    short* __restrict__ pEh, short* __restrict__ pEl,
    short* __restrict__ pQ1h, short* __restrict__ pQ1l,
    short* __restrict__ pQ2h, short* __restrict__ pQ2l)
{
    const int b = blockIdx.x;
    if (b == 0) {
        if (!cnt) return;
        __shared__ int part[256];
        __shared__ int base[257];
        const int t = threadIdx.x;
        const int lo = t * 40, hi = (lo + 40 < N_ATOMS) ? lo + 40 : N_ATOMS;
        int s = 0;
        for (int bb = lo; bb < hi; bb++) s += cnt[bb];
        part[t] = s;
        __syncthreads();
        if (t == 0) {
            int run = 0;
            for (int i = 0; i < 256; i++) { base[i] = run; run += part[i]; }
            base[256] = run;
        }
        __syncthreads();
        int run = base[t];
        for (int bb = lo; bb < hi; bb++) { offs[bb] = run; cur[bb] = run; run += cnt[bb]; }
        if (t == 0) offs[N_ATOMS] = base[256];
        return;
    }
    if (b < 33) {
        const int bb = b - 1;           // 0..31
        const int isW2 = bb >= 16;
        const int idx = (bb - (isW2 ? 16 : 0)) * 256 + threadIdx.x;   // < 4096
        const int j = idx & 7, lane = (idx >> 3) & 63, s2 = (idx >> 9) & 1, ct = idx >> 10;
        const int k = s2 * 32 + (lane >> 4) * 8 + j;
        const int col = ct * 16 + (lane & 15);
        const float wv = wbuf[(isW2 ? W_PPREW2 : W_PPREW1) + k * 64 + col];
        const short hs = f2bs(wv);
        short* dh = isW2 ? w2Fh : w1Fh;
        short* dl = isW2 ? w2Fl : w1Fl;
        dh[idx] = hs;
        dl[idx] = f2bs(wv - bs2f((unsigned short)hs));
        return;
    }
    if (b < 65 || (b >= 97 && b < 129)) {
        // K=128 role (GEMM1 pattern): k = s*32+(lane>>4)*8+j, col = tt*16+(lane&15)
        const int isQ1 = (b >= 97);
        const int idx = (b - (isQ1 ? 97 : 33)) * 256 + threadIdx.x;   // < 8192
        const int j = idx & 7, lane = (idx >> 3) & 63, s = (idx >> 9) & 3, tt = idx >> 11;
        const int k = s * 32 + (lane >> 4) * 8 + j;
        const int col = tt * 16 + (lane & 15);
        const float wv = wbuf[(isQ1 ? W_Q1W : W_PPOSTW1) + k * 64 + col];
        const short hs = f2bs(wv);
        short* dh = isQ1 ? pQ1h : pAh;
        short* dl = isQ1 ? pQ1l : pAl;
        dh[idx] = hs;
        dl[idx] = f2bs(wv - bs2f((unsigned short)hs));
        return;
    }
    if (b < 97) {
        // K=64, 64-col role (w2F pattern): pB (ppW2) or pE (eqW)
        const int isE = b >= 81;
        const int idx = (b - (isE ? 81 : 65)) * 256 + threadIdx.x;    // < 4096
        const int j = idx & 7, lane = (idx >> 3) & 63, s2 = (idx >> 9) & 1, ct = idx >> 10;
        const int k = s2 * 32 + (lane >> 4) * 8 + j;
        const int col = ct * 16 + (lane & 15);
        const float wv = wbuf[(isE ? W_EQW : W_PPOSTW2) + k * 64 + col];
        const short hs = f2bs(wv);
        short* dh = isE ? pEh : pBh;
        short* dl = isE ? pEl : pBl;
        dh[idx] = hs;
        dl[idx] = f2bs(wv - bs2f((unsigned short)hs));
        return;
    }
    {
        // K=64, 128-col role (iiW pattern): pQ2 = q2W
        const int idx = (b - 129) * 256 + threadIdx.x;                // < 8192
        const int j = idx & 7, lane = (idx >> 3) & 63, s2 = (idx >> 9) & 1, ct = idx >> 10;
        const int k = s2 * 32 + (lane >> 4) * 8 + j;
        const int col = ct * 16 + (lane & 15);
        const float wv = wbuf[W_Q2W + k * 128 + col];
        const short hs = f2bs(wv);
        pQ2h[idx] = hs;
        pQ2l[idx] = f2bs(wv - bs2f((unsigned short)hs));
    }
}

// ---------------- pack + MFMA p1_in + scatter (merged launch) ----------------
__global__ __launch_bounds__(256) void k_prep_scatter(
    const float* __restrict__ wbuf,
    short* __restrict__ piWB2,
    short* __restrict__ iiWh, short* __restrict__ iiWl,
    const void* __restrict__ p1, const int* __restrict__ flagp,
    unsigned short* __restrict__ p1h, unsigned short* __restrict__ p1l,
    const int* __restrict__ ind2, int* __restrict__ cur, int* __restrict__ perm,
    const short* __restrict__ w1Fh, const short* __restrict__ w1Fl,
    const short* __restrict__ w2Fh, const short* __restrict__ w2Fl)
{
    __shared__ float hL[64 * 68];
    if (blockIdx.x >= 509) {
        const int p = (blockIdx.x - 509) * 256 + threadIdx.x;
        if (p < N_PAIRS) {
            const int pos = atomicAdd(&cur[ind2[2 * p]], 1);
            perm[pos] = p;
        }
        return;
    }
    if (blockIdx.x < 352) {
        int idx = blockIdx.x * 256 + threadIdx.x;
        if (idx < 81920) {
            const int j = idx & 7, lane = (idx >> 3) & 63, s = (idx >> 9) & 3, T = idx >> 11;
            const int k = s * 32 + (lane >> 4) * 8 + j;
            const int colp = T * 16 + (lane & 15);
            const int b = colp >> 6, c = colp & 63;
            const float v = wbuf[W_PIW + k * 640 + c * 10 + b];
            const short hs = f2bs(v);
            const int cc = idx >> 13, e = idx & 8191;
            piWB2[cc * 16384 + e] = hs;
            piWB2[cc * 16384 + 8192 + e] = f2bs(v - bs2f((unsigned short)hs));
            return;
        }
        idx -= 81920;
        if (idx < 8192) {
            const int j = idx & 7, lane = (idx >> 3) & 63, s2 = (idx >> 9) & 1, ct = idx >> 10;
            const int k = s2 * 32 + (lane >> 4) * 8 + j;
            const int col = ct * 16 + (lane & 15);
            const float wv = wbuf[W_IIW + k * 128 + col];
            const short hs = f2bs(wv);
            iiWh[idx] = hs;
            iiWl[idx] = f2bs(wv - bs2f((unsigned short)hs));
        }
        return;
    }
    // ---- p1_in via MFMA ----
    const int isf32 = *flagp;
    const int t = threadIdx.x;
    const int lane = t & 63, w = t >> 6, lc = lane & 15, quad = lane >> 4;
    const int B0 = (blockIdx.x - 352) * 64;

    bf16x8 xh[2], xl[2];
    {
        const int a = B0 + w * 16 + lc;
        const int ar = (a < N_ATOMS) ? a : N_ATOMS - 1;
        #pragma unroll
        for (int s2 = 0; s2 < 2; s2++) {
            const int base = ar * 64 + s2 * 32 + quad * 8;
            #pragma unroll
            for (int j = 0; j < 8; j++) {
                const float x = ldf(p1, base + j, isf32);
                const short hs = f2bs(x);
                xh[s2][j] = hs;
                xl[s2][j] = f2bs(x - bs2f((unsigned short)hs));
            }
        }
    }
    #pragma unroll
    for (int tt = 0; tt < 4; tt++) {
        f32x4 acc = {0.f, 0.f, 0.f, 0.f};
        #pragma unroll
        for (int s2 = 0; s2 < 2; s2++) {
            bf16x8 bh = *(const bf16x8*)&w1Fh[((tt * 2 + s2) * 64 + lane) * 8];
            bf16x8 bl = *(const bf16x8*)&w1Fl[((tt * 2 + s2) * 64 + lane) * 8];
            acc = __builtin_amdgcn_mfma_f32_16x16x32_bf16(xh[s2], bh, acc, 0, 0, 0);
            acc = __builtin_amdgcn_mfma_f32_16x16x32_bf16(xl[s2], bh, acc, 0, 0, 0);
            acc = __builtin_amdgcn_mfma_f32_16x16x32_bf16(xh[s2], bl, acc, 0, 0, 0);
        }
        const int c = tt * 16 + lc;
        const float b1v = wbuf[W_PPREB1 + c];
        #pragma unroll
        for (int r = 0; r < 4; r++) {
            const int m = w * 16 + quad * 4 + r;
            hL[m * 68 + c] = tanh_fast(acc[r] + b1v);
        }
    }
    __syncthreads();
    bf16x8 hh[2], hl[2];
    {
        const int row = w * 16 + lc;
        #pragma unroll
        for (int s2 = 0; s2 < 2; s2++) {
            const float* pr = &hL[row * 68 + s2 * 32 + quad * 8];
            #pragma unroll
            for (int j = 0; j < 8; j++) {
                const float x = pr[j];
                const short hs = f2bs(x);
                hh[s2][j] = hs;
                hl[s2][j] = f2bs(x - bs2f((unsigned short)hs));
            }
        }
    }
    #pragma unroll
    for (int tt = 0; tt < 4; tt++) {
        f32x4 acc = {0.f, 0.f, 0.f, 0.f};
        #pragma unroll
        for (int s2 = 0; s2 < 2; s2++) {
            bf16x8 bh = *(const bf16x8*)&w2Fh[((tt * 2 + s2) * 64 + lane) * 8];
            bf16x8 bl = *(const bf16x8*)&w2Fl[((tt * 2 + s2) * 64 + lane) * 8];
            acc = __builtin_amdgcn_mfma_f32_16x16x32_bf16(hh[s2], bh, acc, 0, 0, 0);
            acc = __builtin_amdgcn_mfma_f32_16x16x32_bf16(hl[s2], bh, acc, 0, 0, 0);
            acc = __builtin_amdgcn_mfma_f32_16x16x32_bf16(hh[s2], bl, acc, 0, 0, 0);
        }
        const int c = tt * 16 + lc;
        const float b2v = wbuf[W_PPREB2 + c];
        #pragma unroll
        for (int r = 0; r < 4; r++) {
            const int m = w * 16 + quad * 4 + r;
            const int a = B0 + m;
            if (a < N_ATOMS) {
                const float f = tanh_fast(acc[r] + b2v);
                const short hs = f2bs(f);
                p1h[a * 64 + c] = (unsigned short)hs;
                p1l[a * 64 + c] = (unsigned short)f2bs(f - bs2f((unsigned short)hs));
            }
        }
    }
}

// ---------------- fused per-pair MFMA + sorted segment-reduce (unchanged) ----------------
__global__ __launch_bounds__(256) void k_pairs_fused(
    const int* __restrict__ ind2, const void* __restrict__ basis,
    const void* __restrict__ d3, const void* __restrict__ fc,
    const int* __restrict__ perm,
    const void* __restrict__ p3,
    const float* __restrict__ wbuf,
    const short* __restrict__ piWB2,
    const short* __restrict__ iiWh, const short* __restrict__ iiWl,
    const unsigned short* __restrict__ p1h, const unsigned short* __restrict__ p1l,
    const int* __restrict__ flagp, const float* __restrict__ vglob,
    float* __restrict__ p1scat, float* __restrict__ p3acc)
{
    __shared__ __align__(16) char SH[33280];
    __shared__ float basisL[640];
    __shared__ float biasT[640];
    __shared__ int sIL[65], sJL[64];
    __shared__ float d3L[64][3], t3L[64][3], tbL[64];

    unsigned short* Bbuf = (unsigned short*)SH;
    float* preL = (float*)SH;
    float* ipL  = (float*)SH;

    const int t = threadIdx.x;
    const int bid = blockIdx.x;
    const int P0 = ((bid & 7) * 625 + (bid >> 3)) * 64;
    const int isf32 = *flagp;
    const int lane = t & 63;
    const int w = t >> 6;
    const int lc = lane & 15;
    const int quad = lane >> 4;

    if (t < 64) {
        const int p = perm[P0 + t];
        int2 ij = ((const int2*)ind2)[p];
        sIL[t] = ij.x; sJL[t] = ij.y;
        const float vi0 = vglob[ij.x * 3 + 0], vi1 = vglob[ij.x * 3 + 1], vi2 = vglob[ij.x * 3 + 2];
        const float d0 = ldf(d3, 3 * p + 0, isf32);
        const float d1 = ldf(d3, 3 * p + 1, isf32);
        const float d2 = ldf(d3, 3 * p + 2, isf32);
        d3L[t][0] = d0; d3L[t][1] = d1; d3L[t][2] = d2;
        const float proj = vi0 * d0 + vi1 * d1 + vi2 * d2;
        const float w0 = vi0 - proj * d0, w1 = vi1 - proj * d1, w2v = vi2 - proj * d2;
        const float w2 = w0 * w0 + w1 * w1 + w2v * w2v;
        const float g = w2 / (w2 + 1e-4f);
        const float rs = rsqrtf(w2 + 1e-6f);
        t3L[t][0] = w0 * rs * g; t3L[t][1] = w1 * rs * g; t3L[t][2] = w2v * rs * g;
        const float f = ldf(fc, p, isf32);
        tbL[t] = g * f * f;
    }
    if (t == 64) sIL[64] = -1;
    for (int e = t; e < 640; e += 256) {
        const int pm = e / 10, col = e - pm * 10;
        basisL[e] = ldf(basis, perm[P0 + pm] * 10 + col, isf32);
    }
    for (int e = t; e < 640; e += 256) biasT[e] = wbuf[W_PIB + (e & 63) * 10 + (e >> 6)];
    __syncthreads();

    bf16x8 ah[4], al[4];
    {
        const int ia = sIL[w * 16 + lc];
        const int ja = sJL[w * 16 + lc];
        #pragma unroll
        for (int s = 0; s < 4; s++) {
            const int atom = (s < 2) ? ia : ja;
            const int off = atom * 64 + (s & 1) * 32 + quad * 8;
            ah[s] = *(const bf16x8*)(p1h + off);
            al[s] = *(const bf16x8*)(p1l + off);
        }
    }

    float sr[4][4];
    #pragma unroll
    for (int r = 0; r < 4; r++)
        #pragma unroll
        for (int ph = 0; ph < 4; ph++) sr[r][ph] = 0.f;

    for (int cc = 0; cc < 10; cc++) {
        if (cc) __syncthreads();
        {
            const uint4* gsrc = (const uint4*)(piWB2 + cc * 16384);
            uint4* ldst = (uint4*)Bbuf;
            #pragma unroll
            for (int r = 0; r < 8; r++) ldst[r * 256 + t] = gsrc[r * 256 + t];
        }
        __syncthreads();
        #pragma unroll
        for (int tt = 0; tt < 4; tt++) {
            f32x4 acc = {0.f, 0.f, 0.f, 0.f};
            #pragma unroll
            for (int s = 0; s < 4; s++) {
                const int e = ((tt * 4 + s) * 64 + lane) * 8;
                bf16x8 bh = *(const bf16x8*)&Bbuf[e];
                bf16x8 bl = *(const bf16x8*)&Bbuf[8192 + e];
                acc = __builtin_amdgcn_mfma_f32_16x16x32_bf16(ah[s], bh, acc, 0, 0, 0);
                acc = __builtin_amdgcn_mfma_f32_16x16x32_bf16(al[s], bh, acc, 0, 0, 0);
                acc = __builtin_amdgcn_mfma_f32_16x16x32_bf16(ah[s], bl, acc, 0, 0, 0);
            }
            const float bias = biasT[cc * 64 + tt * 16 + lc];
            #pragma unroll
            for (int r = 0; r < 4; r++) {
                const int m = w * 16 + quad * 4 + r;
                const float h = tanh_fast(acc[r] + bias);
                sr[r][tt] += h * basisL[m * 10 + cc];
            }
        }
    }
    __syncthreads();

    #pragma unroll
    for (int r = 0; r < 4; r++)
        #pragma unroll
        for (int ph = 0; ph < 4; ph++)
            preL[(w * 16 + quad * 4 + r) * 68 + ph * 16 + lc] = sr[r][ph];
    __syncthreads();

    bf16x8 ah2[2], al2[2];
    {
        const int row = w * 16 + lc;
        #pragma unroll
        for (int s2 = 0; s2 < 2; s2++) {
            const float* pr2 = &preL[row * 68 + s2 * 32 + quad * 8];
            #pragma unroll
            for (int j = 0; j < 8; j++) {
                const float x = pr2[j];
                const short hs = f2bs(x);
                ah2[s2][j] = hs;
                al2[s2][j] = f2bs(x - bs2f((unsigned short)hs));
            }
        }
    }
    __syncthreads();

    float pv0[16];
    if (t < 192) {
        #pragma unroll
        for (int u = 0; u < 16; u++) pv0[u] = ldf(p3, sJL[u] * 192 + t, isf32);
    }

    #pragma unroll
    for (int ct = 0; ct < 8; ct++) {
        f32x4 acc = {0.f, 0.f, 0.f, 0.f};
        #pragma unroll
        for (int s2 = 0; s2 < 2; s2++) {
            bf16x8 bh = *(const bf16x8*)&iiWh[((ct * 2 + s2) * 64 + lane) * 8];
            bf16x8 bl = *(const bf16x8*)&iiWl[((ct * 2 + s2) * 64 + lane) * 8];
            acc = __builtin_amdgcn_mfma_f32_16x16x32_bf16(ah2[s2], bh, acc, 0, 0, 0);
            acc = __builtin_amdgcn_mfma_f32_16x16x32_bf16(al2[s2], bh, acc, 0, 0, 0);
            acc = __builtin_amdgcn_mfma_f32_16x16x32_bf16(ah2[s2], bl, acc, 0, 0, 0);
        }
        const int ch = ct * 16 + lc;
        #pragma unroll
        for (int r = 0; r < 4; r++) {
            const int m = w * 16 + quad * 4 + r;
            ipL[m * 130 + ch] = tanh_fast(acc[r]);
        }
    }
    __syncthreads();

    if (t < 192) {
        const int x = t >> 6, cc2 = t & 63;
        float acc = 0.f;
        #pragma unroll
        for (int blk = 0; blk < 4; blk++) {
            float pv[16];
            if (blk == 0) {
                #pragma unroll
                for (int u = 0; u < 16; u++) pv[u] = pv0[u];
            } else {
                #pragma unroll
                for (int u = 0; u < 16; u++)
                    pv[u] = ldf(p3, sJL[blk * 16 + u] * 192 + t, isf32);
            }
            #pragma unroll
            for (int u = 0; u < 16; u++) {
                const int m = blk * 16 + u;
                const float ipb = ipL[m * 130 + 64 + cc2];
                acc += (pv[u] + d3L[m][x]) * ipb + t3L[m][x] * (ipb * tbL[m]);
                if (sIL[m + 1] != sIL[m]) {
                    atomicAdd(&p3acc[(size_t)sIL[m] * 192 + t], acc);
                    acc = 0.f;
                }
            }
        }
    } else {
        const int ch0 = t - 192;
        float a0 = 0.f, a1 = 0.f;
        #pragma unroll 8
        for (int m = 0; m < 64; m++) {
            a0 += ipL[m * 130 + ch0];
            a1 += ipL[m * 130 + 64 + ch0];
            if (sIL[m + 1] != sIL[m]) {
                const size_t base = (size_t)sIL[m] * 128;
                atomicAdd(&p1scat[base + ch0], a0);
                atomicAdd(&p1scat[base + 64 + ch0], a1);
                a0 = 0.f; a1 = 0.f;
            }
        }
    }
}

// ---------------- legacy atomic-path per-pair kernel (fallback) ----------------
__global__ __launch_bounds__(256) void k_pairs_atomic(
    const int* __restrict__ ind2, const void* __restrict__ basis,
    const void* __restrict__ d3, const void* __restrict__ fc,
    const void* __restrict__ p3,
    const float* __restrict__ wbuf,
    const short* __restrict__ piWB2,
    const short* __restrict__ iiWh, const short* __restrict__ iiWl,
    const unsigned short* __restrict__ p1h, const unsigned short* __restrict__ p1l,
    const int* __restrict__ flagp, const float* __restrict__ vglob,
    float* __restrict__ outA, float* __restrict__ outB)
{
    __shared__ __align__(16) unsigned short Bbuf[8192];
    __shared__ __align__(16) char SH[17408];
    __shared__ float basisL[640];
    __shared__ int sIL[64], sJL[64];
    __shared__ float d3L[64][3], t3L[64][3], tbL[64];

    float* preL = (float*)SH;
    float* i1bL = (float*)SH;

    const int t = threadIdx.x;
    const int P0 = blockIdx.x * 64;
    const int isf32 = *flagp;
    const int lane = t & 63;
    const int w = t >> 6;
    const int lc = lane & 15;
    const int quad = lane >> 4;

    if (t < 64) {
        int2 ij = ((const int2*)ind2)[P0 + t];
        sIL[t] = ij.x; sJL[t] = ij.y;
    }
    for (int e = t; e < 640; e += 256) basisL[e] = ldf(basis, P0 * 10 + e, isf32);
    __syncthreads();

    bf16x8 ah[4], al[4];
    {
        const int ia = sIL[w * 16 + lc];
        const int ja = sJL[w * 16 + lc];
        #pragma unroll
        for (int s = 0; s < 4; s++) {
            const int atom = (s < 2) ? ia : ja;
            const int off = atom * 64 + (s & 1) * 32 + quad * 8;
            ah[s] = *(const bf16x8*)(p1h + off);
            al[s] = *(const bf16x8*)(p1l + off);
        }
    }

    float sr[4][4];
    #pragma unroll
    for (int r = 0; r < 4; r++)
        #pragma unroll
        for (int ph = 0; ph < 4; ph++) sr[r][ph] = 0.f;

    for (int cc = 0; cc < 10; cc++) {
        f32x4 acc[4];
        #pragma unroll
        for (int tt = 0; tt < 4; tt++) acc[tt] = (f32x4){0.f, 0.f, 0.f, 0.f};

        __syncthreads();
        {
            const uint4* gsrc = (const uint4*)(piWB2 + cc * 16384);
            uint4* ldst = (uint4*)Bbuf;
            #pragma unroll
            for (int r = 0; r < 4; r++) ldst[r * 256 + t] = gsrc[r * 256 + t];
        }
        __syncthreads();
        #pragma unroll
        for (int tt = 0; tt < 4; tt++) {
            #pragma unroll
            for (int s = 0; s < 4; s++) {
                bf16x8 bfr = *(const bf16x8*)&Bbuf[((tt * 4 + s) * 64 + lane) * 8];
                acc[tt] = __builtin_amdgcn_mfma_f32_16x16x32_bf16(ah[s], bfr, acc[tt], 0, 0, 0);
                acc[tt] = __builtin_amdgcn_mfma_f32_16x16x32_bf16(al[s], bfr, acc[tt], 0, 0, 0);
            }
        }
        __syncthreads();
        {
            const uint4* gsrc = (const uint4*)(piWB2 + cc * 16384 + 8192);
            uint4* ldst = (uint4*)Bbuf;
            #pragma unroll
            for (int r = 0; r < 4; r++) ldst[r * 256 + t] = gsrc[r * 256 + t];
        }
        __syncthreads();
        #pragma unroll
        for (int tt = 0; tt < 4; tt++) {
            #pragma unroll
            for (int s = 0; s < 4; s++) {
                bf16x8 bfr = *(const bf16x8*)&Bbuf[((tt * 4 + s) * 64 + lane) * 8];
                acc[tt] = __builtin_amdgcn_mfma_f32_16x16x32_bf16(ah[s], bfr, acc[tt], 0, 0, 0);
            }
            const int c = tt * 16 + lc;
            const float bias = wbuf[W_PIB + c * 10 + cc];
            #pragma unroll
            for (int r = 0; r < 4; r++) {
                const int m = w * 16 + quad * 4 + r;
                const float h = tanh_fast(acc[tt][r] + bias);
                sr[r][tt] += h * basisL[m * 10 + cc];
            }
        }
    }

    #pragma unroll
    for (int r = 0; r < 4; r++)
        #pragma unroll
        for (int ph = 0; ph < 4; ph++)
            preL[(w * 16 + quad * 4 + r) * 68 + ph * 16 + lc] = sr[r][ph];
    __syncthreads();

    bf16x8 ah2[2], al2[2];
    {
        const int row = w * 16 + lc;
        #pragma unroll
        for (int s2 = 0; s2 < 2; s2++) {
            const float* pr2 = &preL[row * 68 + s2 * 32 + quad * 8];
            #pragma unroll
            for (int j = 0; j < 8; j++) {
                const float x = pr2[j];
                const short hs = f2bs(x);
                ah2[s2][j] = hs;
                al2[s2][j] = f2bs(x - bs2f((unsigned short)hs));
            }
        }
    }
    __syncthreads();

    #pragma unroll
    for (int ct = 0; ct < 8; ct++) {
        f32x4 acc = {0.f, 0.f, 0.f, 0.f};
        #pragma unroll
        for (int s2 = 0; s2 < 2; s2++) {
            bf16x8 bh = *(const bf16x8*)&iiWh[((ct * 2 + s2) * 64 + lane) * 8];
            bf16x8 bl = *(const bf16x8*)&iiWl[((ct * 2 + s2) * 64 + lane) * 8];
            acc = __builtin_amdgcn_mfma_f32_16x16x32_bf16(ah2[s2], bh, acc, 0, 0, 0);
            acc = __builtin_amdgcn_mfma_f32_16x16x32_bf16(al2[s2], bh, acc, 0, 0, 0);
            acc = __builtin_amdgcn_mfma_f32_16x16x32_bf16(ah2[s2], bl, acc, 0, 0, 0);
        }
        const int ch = ct * 16 + lc;
        #pragma unroll
        for (int r = 0; r < 4; r++) {
            const int m = w * 16 + quad * 4 + r;
            const float val = tanh_fast(acc[r]);
            atomicAdd(&outA[(size_t)sIL[m] * 128 + ch], val);
            if (ch >= 64) i1bL[m * 64 + (ch - 64)] = val;
        }
    }

    __syncthreads();
    if (t < 64) {
        const int m = t;
        const int ia = sIL[m];
        const float vi0 = vglob[ia * 3 + 0], vi1 = vglob[ia * 3 + 1], vi2 = vglob[ia * 3 + 2];
        const float d0 = ldf(d3, (P0 + m) * 3 + 0, isf32);
        const float d1 = ldf(d3, (P0 + m) * 3 + 1, isf32);
        const float d2 = ldf(d3, (P0 + m) * 3 + 2, isf32);
        d3L[m][0] = d0; d3L[m][1] = d1; d3L[m][2] = d2;
        const float proj = vi0 * d0 + vi1 * d1 + vi2 * d2;
        const float w0 = vi0 - proj * d0, w1 = vi1 - proj * d1, w2v = vi2 - proj * d2;
        const float w2 = w0 * w0 + w1 * w1 + w2v * w2v;
        const float g = w2 / (w2 + 1e-4f);
        const float rs = rsqrtf(w2 + 1e-6f);
        t3L[m][0] = w0 * rs * g; t3L[m][1] = w1 * rs * g; t3L[m][2] = w2v * rs * g;
        const float f = ldf(fc, P0 + m, isf32);
        tbL[m] = g * f * f;
    }
    __syncthreads();
    const int c = lane;
    #pragma unroll 4
    for (int mm = 0; mm < 16; mm++) {
        const int m = w * 16 + mm;
        const float bv = i1bL[m * 64 + c];
        const float coef = bv * tbL[m];
        #pragma unroll
        for (int x = 0; x < 3; x++) {
            const float p3v = ldf(p3, sJL[m] * 192 + x * 64 + c, isf32);
            atomicAdd(&outB[(size_t)sIL[m] * 192 + x * 64 + c],
                      p3v * bv + d3L[m][x] * bv + t3L[m][x] * coef);
        }
    }
}

// ---------------- per-atom epilogue via MFMA (64 atoms/block, 157 blocks) ----------------
// Replaces the scalar k_final (~1.6GB L2 weight re-reads / ~46us floor) with
// 5 small GEMMs on pre-packed bf16 hi/lo fragments (~21MB traffic).
__global__ __launch_bounds__(256) void k_final_mfma(
    const float* __restrict__ p1scat, const float* __restrict__ p3acc,
    const float* __restrict__ wbuf, const int* __restrict__ flagp,
    const short* __restrict__ pAh, const short* __restrict__ pAl,
    const short* __restrict__ pBh, const short* __restrict__ pBl,
    const short* __restrict__ pEh, const short* __restrict__ pEl,
    const short* __restrict__ pQ1h, const short* __restrict__ pQ1l,
    const short* __restrict__ pQ2h, const short* __restrict__ pQ2l,
    void* __restrict__ out)
{
    __shared__ float hL[64 * 68];     // hA, later hB (stride 68: 2-way bank = free)
    __shared__ float catL[64 * 132];  // [p1n | dot] (stride 132: 2-way bank)
    const int isf32 = *flagp;
    const int t = threadIdx.x;
    const int lane = t & 63, w = t >> 6, lc = lane & 15, quad = lane >> 4;
    const int B0 = blockIdx.x * 64;
    const int arow = B0 + w * 16 + lc;
    const int ar = (arow < N_ATOMS) ? arow : N_ATOMS - 1;   // clamp OOB loads

    // ---- GEMM 1: hA = tanh(p1scat @ ppW1), K=128 ----
    {
        bf16x8 xh[4], xl[4];
        #pragma unroll
        for (int s = 0; s < 4; s++) {
            const float* src = p1scat + (size_t)ar * 128 + s * 32 + quad * 8;
            #pragma unroll
            for (int j = 0; j < 8; j++) {
                const float x = src[j];
                const short hs = f2bs(x);
                xh[s][j] = hs;
                xl[s][j] = f2bs(x - bs2f((unsigned short)hs));
            }
        }
        #pragma unroll
        for (int tt = 0; tt < 4; tt++) {
            f32x4 acc = {0.f, 0.f, 0.f, 0.f};
            #pragma unroll
            for (int s = 0; s < 4; s++) {
                bf16x8 bh = *(const bf16x8*)&pAh[((tt * 4 + s) * 64 + lane) * 8];
                bf16x8 bl = *(const bf16x8*)&pAl[((tt * 4 + s) * 64 + lane) * 8];
                acc = __builtin_amdgcn_mfma_f32_16x16x32_bf16(xh[s], bh, acc, 0, 0, 0);
                acc = __builtin_amdgcn_mfma_f32_16x16x32_bf16(xl[s], bh, acc, 0, 0, 0);
                acc = __builtin_amdgcn_mfma_f32_16x16x32_bf16(xh[s], bl, acc, 0, 0, 0);
            }
            const int c = tt * 16 + lc;
            #pragma unroll
            for (int r = 0; r < 4; r++)
                hL[(w * 16 + quad * 4 + r) * 68 + c] = tanh_fast(acc[r]);
        }
    }
    __syncthreads();

    // ---- GEMM 2: p1n = tanh(hA @ ppW2) -> catL[:,0:64] ----
    {
        bf16x8 hh[2], hl[2];
        const int row = w * 16 + lc;
        #pragma unroll
        for (int s2 = 0; s2 < 2; s2++) {
            const float* pr = &hL[row * 68 + s2 * 32 + quad * 8];
            #pragma unroll
            for (int j = 0; j < 8; j++) {
                const float x = pr[j];
                const short hs = f2bs(x);
                hh[s2][j] = hs;
                hl[s2][j] = f2bs(x - bs2f((unsigned short)hs));
            }
        }
        #pragma unroll
        for (int tt = 0; tt < 4; tt++) {
            f32x4 acc = {0.f, 0.f, 0.f, 0.f};
            #pragma unroll
            for (int s2 = 0; s2 < 2; s2++) {
                bf16x8 bh = *(const bf16x8*)&pBh[((tt * 2 + s2) * 64 + lane) * 8];
                bf16x8 bl = *(const bf16x8*)&pBl[((tt * 2 + s2) * 64 + lane) * 8];
                acc = __builtin_amdgcn_mfma_f32_16x16x32_bf16(hh[s2], bh, acc, 0, 0, 0);
                acc = __builtin_amdgcn_mfma_f32_16x16x32_bf16(hl[s2], bh, acc, 0, 0, 0);
                acc = __builtin_amdgcn_mfma_f32_16x16x32_bf16(hh[s2], bl, acc, 0, 0, 0);
            }
            const int c = tt * 16 + lc;
            #pragma unroll
            for (int r = 0; r < 4; r++)
                catL[(w * 16 + quad * 4 + r) * 132 + c] = tanh_fast(acc[r]);
        }
    }

    // ---- GEMM 3 (x3): pn[x] = p3acc_x @ eqW; retained in regs for the epilogue ----
    float pn[3][4][4];
    #pragma unroll
    for (int x = 0; x < 3; x++) {
        bf16x8 ph[2], pl[2];
        #pragma unroll
        for (int s2 = 0; s2 < 2; s2++) {
            const float* src = p3acc + (size_t)ar * 192 + x * 64 + s2 * 32 + quad * 8;
            #pragma unroll
            for (int j = 0; j < 8; j++) {
                const float xv = src[j];
                const short hs = f2bs(xv);
                ph[s2][j] = hs;
                pl[s2][j] = f2bs(xv - bs2f((unsigned short)hs));
            }
        }
        #pragma unroll
        for (int tt = 0; tt < 4; tt++) {
            f32x4 acc = {0.f, 0.f, 0.f, 0.f};
            #pragma unroll
            for (int s2 = 0; s2 < 2; s2++) {
                bf16x8 bh = *(const bf16x8*)&pEh[((tt * 2 + s2) * 64 + lane) * 8];
                bf16x8 bl = *(const bf16x8*)&pEl[((tt * 2 + s2) * 64 + lane) * 8];
                acc = __builtin_amdgcn_mfma_f32_16x16x32_bf16(ph[s2], bh, acc, 0, 0, 0);
                acc = __builtin_amdgcn_mfma_f32_16x16x32_bf16(pl[s2], bh, acc, 0, 0, 0);
                acc = __builtin_amdgcn_mfma_f32_16x16x32_bf16(ph[s2], bl, acc, 0, 0, 0);
            }
            #pragma unroll
            for (int r = 0; r < 4; r++) pn[x][tt][r] = acc[r];
        }
    }
    // dot -> catL[:,64:128]
    #pragma unroll
    for (int tt = 0; tt < 4; tt++) {
        const int c = tt * 16 + lc;
        #pragma unroll
        for (int r = 0; r < 4; r++) {
            const float d = pn[0][tt][r] * pn[0][tt][r]
                          + pn[1][tt][r] * pn[1][tt][r]
                          + pn[2][tt][r] * pn[2][tt][r];
            catL[(w * 16 + quad * 4 + r) * 132 + 64 + c] = d;
        }
    }
    __syncthreads();   // catL complete; prior hL reads done -> hL reusable

    // ---- GEMM 4: hB = tanh(cat @ q1W + q1b), K=128 -> hL ----
    {
        bf16x8 ch[4], cl[4];
        const int row = w * 16 + lc;
        #pragma unroll
        for (int s = 0; s < 4; s++) {
            const float* pr = &catL[row * 132 + s * 32 + quad * 8];
            #pragma unroll
            for (int j = 0; j < 8; j++) {
                const float x = pr[j];
                const short hs = f2bs(x);
                ch[s][j] = hs;
                cl[s][j] = f2bs(x - bs2f((unsigned short)hs));
            }
        }
        #pragma unroll
        for (int tt = 0; tt < 4; tt++) {
            f32x4 acc = {0.f, 0.f, 0.f, 0.f};
            #pragma unroll
            for (int s = 0; s < 4; s++) {
                bf16x8 bh = *(const bf16x8*)&pQ1h[((tt * 4 + s) * 64 + lane) * 8];
                bf16x8 bl = *(const bf16x8*)&pQ1l[((tt * 4 + s) * 64 + lane) * 8];
                acc = __builtin_amdgcn_mfma_f32_16x16x32_bf16(ch[s], bh, acc, 0, 0, 0);
                acc = __builtin_amdgcn_mfma_f32_16x16x32_bf16(cl[s], bh, acc, 0, 0, 0);
                acc = __builtin_amdgcn_mfma_f32_16x16x32_bf16(ch[s], bl, acc, 0, 0, 0);
            }
            const int c = tt * 16 + lc;
            const float b1v = wbuf[W_Q1B + c];
            #pragma unroll
            for (int r = 0; r < 4; r++)
                hL[(w * 16 + quad * 4 + r) * 68 + c] = tanh_fast(acc[r] + b1v);
        }
    }
    __syncthreads();

    // ---- GEMM 5: g = tanh(hB @ q2W + q2b), N=128; fused output write ----
    bf16x8 gh[2], gl[2];
    {
        const int row = w * 16 + lc;
        #pragma unroll
        for (int s2 = 0; s2 < 2; s2++) {
            const float* pr = &hL[row * 68 + s2 * 32 + quad * 8];
            #pragma unroll
            for (int j = 0; j < 8; j++) {
                const float x = pr[j];
                const short hs = f2bs(x);
                gh[s2][j] = hs;
                gl[s2][j] = f2bs(x - bs2f((unsigned short)hs));
            }
        }
    }
    float* p1o32 = (float*)out;
    float* p3o32 = p1o32 + 640000;
    __hip_bfloat16* p1o16 = (__hip_bfloat16*)out;
    __hip_bfloat16* p3o16 = p1o16 + 640000;
    #pragma unroll
    for (int ct = 0; ct < 8; ct++) {
        f32x4 acc = {0.f, 0.f, 0.f, 0.f};
        #pragma unroll
        for (int s2 = 0; s2 < 2; s2++) {
            bf16x8 bh = *(const bf16x8*)&pQ2h[((ct * 2 + s2) * 64 + lane) * 8];
            bf16x8 bl = *(const bf16x8*)&pQ2l[((ct * 2 + s2) * 64 + lane) * 8];
            acc = __builtin_amdgcn_mfma_f32_16x16x32_bf16(gh[s2], bh, acc, 0, 0, 0);
            acc = __builtin_amdgcn_mfma_f32_16x16x32_bf16(gl[s2], bh, acc, 0, 0, 0);
            acc = __builtin_amdgcn_mfma_f32_16x16x32_bf16(gh[s2], bl, acc, 0, 0, 0);
        }
        const int col = ct * 16 + lc;
        const float qb = wbuf[W_Q2B + col];
        #pragma unroll
        for (int r = 0; r < 4; r++) {
            const int m = w * 16 + quad * 4 + r;
            const int a = B0 + m;
            if (a >= N_ATOMS) continue;
            const float val = tanh_fast(acc[r] + qb);
            if (ct < 4) {
                if (isf32) p1o32[a * 64 + col] = val;
                else       p1o16[a * 64 + col] = __float2bfloat16(val);
            } else {
                const int c2 = col - 64;          // p3 channel; pn tt index = ct-4
                #pragma unroll
                for (int x = 0; x < 3; x++) {
                    const float pv = pn[x][ct - 4][r] * val;
                    if (isf32) p3o32[a * 192 + x * 64 + c2] = pv;
                    else       p3o16[a * 192 + x * 64 + c2] = __float2bfloat16(pv);
                }
            }
        }
    }
}

extern "C" void kernel_launch(void* const* d_in, const int* in_sizes, int n_in,
                              void* d_out, int out_size, void* d_ws, size_t ws_size,
                              hipStream_t stream)
{
    const int* ind2 = (const int*)d_in[0];
    const void* p1    = d_in[1];
    const void* p3    = d_in[2];
    const void* basis = d_in[3];
    const void* d3    = d_in[4];
    const void* fc    = d_in[5];

    char* W = (char*)d_ws;
    float* wbuf  = (float*)(W + 0);                       // 528128 B
    short* piWB2 = (short*)(W + 528128);                  // 655360 B -> 1183488
    short* iiWh  = (short*)(W + 1183488);                 // 16384 B -> 1199872
    short* iiWl  = (short*)(W + 1199872);                 // 16384 B -> 1216256
    unsigned short* p1h = (unsigned short*)(W + 1216256); // 1280000 B -> 2496256
    unsigned short* p1l = (unsigned short*)(W + 2496256); // 1280000 B -> 3776256
    int* flag = (int*)(W + 3776256);                      // 64 B -> 3776320
    short* w1Fh = (short*)(W + 3776320);                  // 8192 B -> 3784512
    short* w1Fl = (short*)(W + 3784512);                  // 8192 B -> 3792704
    short* w2Fh = (short*)(W + 3792704);                  // 8192 B -> 3800896
    short* w2Fl = (short*)(W + 3800896);                  // 8192 B -> 3809088
    short* pAh  = (short*)(W + 3809088);                  // 16384 B -> 3825472
    short* pAl  = (short*)(W + 3825472);                  // 16384 B -> 3841856
    short* pBh  = (short*)(W + 3841856);                  // 8192 B -> 3850048
    short* pBl  = (short*)(W + 3850048);                  // 8192 B -> 3858240
    short* pEh  = (short*)(W + 3858240);                  // 8192 B -> 3866432
    short* pEl  = (short*)(W + 3866432);                  // 8192 B -> 3874624
    short* pQ1h = (short*)(W + 3874624);                  // 16384 B -> 3891008
    short* pQ1l = (short*)(W + 3891008);                  // 16384 B -> 3907392
    short* pQ2h = (short*)(W + 3907392);                  // 16384 B -> 3923776
    short* pQ2l = (short*)(W + 3923776);                  // 16384 B -> 3940160

    const int fused = (ws_size >= 18260224ULL) ? 1 : 0;

    if (fused) {
        int* offs     = (int*)(W + 3940160);      // 40016 B -> pad 3980224
        int* cur      = (int*)(W + 3980224);      // 40000 B -> 4020224
        int* perm     = (int*)(W + 4020224);      // 1280000 B -> 5300224
        int* cnt      = (int*)(W + 5300224);      // 40000 B -> 5340224
        float* v      = (float*)(W + 5340224);    // 120000 B -> 5460224
        float* p1scat = (float*)(W + 5460224);    // 5120000 B -> 10580224
        float* p3acc  = (float*)(W + 10580224);   // 7680000 B -> ends 18260224

        // one contiguous zero: cnt + v + p1scat + p3acc
        hipMemsetAsync(cnt, 0, 40000 + 120000 + 5120000 + 7680000, stream);
        k_front<<<1766, 256, 0, stream>>>(d3, fc, flag, ind2, cnt, v,
            d_in[6], d_in[7], d_in[8], d_in[9], d_in[10], d_in[11], d_in[12],
            d_in[13], d_in[14], d_in[15], d_in[16], d_in[17], d_in[18], d_in[19],
            wbuf);
        k_scan_wfrag<<<161, 256, 0, stream>>>(cnt, offs, cur, wbuf,
                                              w1Fh, w1Fl, w2Fh, w2Fl,
                                              pAh, pAl, pBh, pBl, pEh, pEl,
                                              pQ1h, pQ1l, pQ2h, pQ2l);
        k_prep_scatter<<<1759, 256, 0, stream>>>(wbuf, piWB2, iiWh, iiWl, p1, flag,
                                                 p1h, p1l, ind2, cur, perm,
                                                 w1Fh, w1Fl, w2Fh, w2Fl);
        k_pairs_fused<<<5000, 256, 0, stream>>>(ind2, basis, d3, fc, perm, p3,
                                                wbuf, piWB2, iiWh, iiWl,
                                                p1h, p1l, flag, v, p1scat, p3acc);
        k_final_mfma<<<157, 256, 0, stream>>>(p1scat, p3acc, wbuf, flag,
                                              pAh, pAl, pBh, pBl, pEh, pEl,
                                              pQ1h, pQ1l, pQ2h, pQ2l, d_out);
    } else {
        int* cnt      = (int*)(W + 3940160);      // 40000 B -> 3980160
        float* v      = (float*)(W + 3980160);    // 120000 B -> 4100160
        float* p1scat = (float*)(W + 4100160);    // 5120000 B -> 9220160
        float* p3acc  = (float*)(W + 9220160);    // 7680000 B -> ends 16900160

        hipMemsetAsync(cnt, 0, 40000 + 120000 + 5120000 + 7680000, stream);
        k_front<<<1766, 256, 0, stream>>>(d3, fc, flag, ind2, cnt, v,
            d_in[6], d_in[7], d_in[8], d_in[9], d_in[10], d_in[11], d_in[12],
            d_in[13], d_in[14], d_in[15], d_in[16], d_in[17], d_in[18], d_in[19],
            wbuf);
        k_scan_wfrag<<<161, 256, 0, stream>>>(nullptr, nullptr, nullptr, wbuf,
                                              w1Fh, w1Fl, w2Fh, w2Fl,
                                              pAh, pAl, pBh, pBl, pEh, pEl,
                                              pQ1h, pQ1l, pQ2h, pQ2l);
        k_prep_scatter<<<509, 256, 0, stream>>>(wbuf, piWB2, iiWh, iiWl, p1, flag,
                                                p1h, p1l, nullptr, nullptr, nullptr,
                                                w1Fh, w1Fl, w2Fh, w2Fl);
        k_pairs_atomic<<<5000, 256, 0, stream>>>(ind2, basis, d3, fc, p3,
                                                 wbuf, piWB2, iiWh, iiWl,
                                                 p1h, p1l, flag, v,
                                                 p1scat, p3acc);
        k_final_mfma<<<157, 256, 0, stream>>>(p1scat, p3acc, wbuf, flag,
                                              pAh, pAl, pBh, pBl, pEh, pEl,
                                              pQ1h, pQ1l, pQ2h, pQ2l, d_out);
    }
}

// Round 11
// 458.677 us; speedup vs baseline: 1.1398x; 1.0571x over previous
//
#include <hip/hip_runtime.h>
#include <hip/hip_bf16.h>

#define N_ATOMS 10000
#define N_PAIRS 320000
#define C_ 64
#define NB_ 10

typedef short bf16x8 __attribute__((ext_vector_type(8)));
typedef float f32x4 __attribute__((ext_vector_type(4)));

__device__ __forceinline__ float bf2f(__hip_bfloat16 x) { return __bfloat162float(x); }
__device__ __forceinline__ float ldf(const void* p, int i, int isf32) {
    return isf32 ? ((const float*)p)[i] : bf2f(((const __hip_bfloat16*)p)[i]);
}
__device__ __forceinline__ short f2bs(float x) {
    __hip_bfloat16 h = __float2bfloat16(x);
    return *reinterpret_cast<short*>(&h);
}
__device__ __forceinline__ float bs2f(unsigned short s) {
    return __uint_as_float(((unsigned)s) << 16);
}
// fast tanh: 1 - 2/(exp(2x)+1). err ~1e-6, saturates correctly at +-inf.
__device__ __forceinline__ float tanh_fast(float x) {
    const float e = __expf(2.0f * x);
    return 1.0f - 2.0f * __builtin_amdgcn_rcpf(e + 1.0f);
}

// wbuf f32 offsets
#define W_PPREW1 0
#define W_PPREB1 4096
#define W_PPREW2 4160
#define W_PPREB2 8256
#define W_PIW    8320
#define W_PIB    90240
#define W_IIW    90880
#define W_PPOSTW1 99072
#define W_PPOSTW2 107264
#define W_EQW    111360
#define W_Q1W    115456
#define W_Q1B    123648
#define W_Q2W    123712
#define W_Q2B    131904
#define W_TOTAL  132032

__device__ __forceinline__ int probe_eval(const void* d3)
{
    float sf = 0.f, sb = 0.f;
    const float* f = (const float*)d3;
    const __hip_bfloat16* b = (const __hip_bfloat16*)d3;
    for (int r = 0; r < 4; r++) {
        float x = f[r*3], y = f[r*3+1], z = f[r*3+2];
        float n = x*x + y*y + z*z;
        sf += isfinite(n) ? fabsf(n - 1.f) : 1e30f;
        float xb = bf2f(b[r*3]), yb = bf2f(b[r*3+1]), zb = bf2f(b[r*3+2]);
        float nb = xb*xb + yb*yb + zb*zb;
        sb += isfinite(nb) ? fabsf(nb - 1.f) : 1e30f;
    }
    return (sf < sb) ? 1 : 0;
}

// ---------------- probe (fallback path helper) ----------------
__global__ void k_probe(const void* __restrict__ d3, int* __restrict__ flag)
{
    if (threadIdx.x == 0 && blockIdx.x == 0) *flag = probe_eval(d3);
}

// ---------------- front kernel: hist+v+rank || convert || ALL weight packs ----------------
// Packs read the RAW weight tensors (value-identical to the old wbuf round-trip)
// so they run concurrently with hist/convert instead of serialized behind them.
// Block map:
//   [0,1250)     hist + v + rank (rank = return of the cnt atomicAdd)
//   [1250,1766)  wbuf convert (biases etc. still needed by consumers)
//   [1766,2086)  piWB2 pack (from pi_W = s4)
//   [2086,2118)  iiWh/iiWl pack (from ii_W = s6)
//   [2118,2150)  w1F/w2F pack (from pp_pre_W1 = s0 / pp_pre_W2 = s2)
//   [2150,2182)  pA (pp_post_W1 = s7, K=128 role)
//   [2182,2198)  pB (pp_post_W2 = s8, K=64 role)
//   [2198,2214)  pE (eq_pp_W = s9,    K=64 role)
//   [2214,2246)  pQ1 (pp1_W1 = s10,   K=128 role)
//   [2246,2278)  pQ2 (pp1_W2 = s12,   K=64 N=128 role)
__global__ __launch_bounds__(256) void k_front(
    const void* __restrict__ d3, const void* __restrict__ fc,
    int* __restrict__ flag, const int* __restrict__ ind2,
    int* __restrict__ cnt, float* __restrict__ v, int* __restrict__ rank,
    const void* s0, const void* s1, const void* s2, const void* s3,
    const void* s4, const void* s5, const void* s6, const void* s7,
    const void* s8, const void* s9, const void* s10, const void* s11,
    const void* s12, const void* s13,
    float* __restrict__ wbuf,
    short* __restrict__ piWB2,
    short* __restrict__ iiWh, short* __restrict__ iiWl,
    short* __restrict__ w1Fh, short* __restrict__ w1Fl,
    short* __restrict__ w2Fh, short* __restrict__ w2Fl,
    short* __restrict__ pAh, short* __restrict__ pAl,
    short* __restrict__ pBh, short* __restrict__ pBl,
    short* __restrict__ pEh, short* __restrict__ pEl,
    short* __restrict__ pQ1h, short* __restrict__ pQ1l,
    short* __restrict__ pQ2h, short* __restrict__ pQ2l)
{
    __shared__ int fsh;
    if (threadIdx.x == 0) {
        const int fv = probe_eval(d3);
        fsh = fv;
        if (blockIdx.x == 0) *flag = fv;
    }
    __syncthreads();
    const int isf32 = fsh;
    const int b = blockIdx.x;
    const int t = threadIdx.x;

    if (b < 1250) {
        const int p = b * 256 + t;
        if (p >= N_PAIRS) return;
        const int ia = ind2[2 * p];
        rank[p] = atomicAdd(&cnt[ia], 1);
        const float f = ldf(fc, p, isf32);
        #pragma unroll
        for (int x = 0; x < 3; x++)
            atomicAdd(&v[ia * 3 + x], ldf(d3, 3 * p + x, isf32) * f);
        return;
    }
    if (b < 1766) {
        const int idx = (b - 1250) * 256 + t;
        if (idx >= W_TOTAL) return;
        const int offw[15] = {W_PPREW1, W_PPREB1, W_PPREW2, W_PPREB2, W_PIW, W_PIB,
                              W_IIW, W_PPOSTW1, W_PPOSTW2, W_EQW, W_Q1W, W_Q1B,
                              W_Q2W, W_Q2B, W_TOTAL};
        const void* srcs[14] = {s0,s1,s2,s3,s4,s5,s6,s7,s8,s9,s10,s11,s12,s13};
        int q = 0;
        while (idx >= offw[q + 1]) q++;
        wbuf[idx] = ldf(srcs[q], idx - offw[q], isf32);
        return;
    }
    if (b < 2086) {
        // piWB2: merged per-cc 32KB hi|lo tiles from pi_W (128 x 640)
        const int idx = (b - 1766) * 256 + t;                 // < 81920
        const int j = idx & 7, lane = (idx >> 3) & 63, sgrp = (idx >> 9) & 3, T = idx >> 11;
        const int k = sgrp * 32 + (lane >> 4) * 8 + j;
        const int colp = T * 16 + (lane & 15);
        const int bb = colp >> 6, c = colp & 63;
        const float wv = ldf(s4, k * 640 + c * 10 + bb, isf32);
        const short hs = f2bs(wv);
        const int cc = idx >> 13, e = idx & 8191;
        piWB2[cc * 16384 + e] = hs;
        piWB2[cc * 16384 + 8192 + e] = f2bs(wv - bs2f((unsigned short)hs));
        return;
    }
    if (b < 2118) {
        // iiW pack from ii_W (64 x 128)
        const int idx = (b - 2086) * 256 + t;                 // < 8192
        const int j = idx & 7, lane = (idx >> 3) & 63, sgrp = (idx >> 9) & 1, ct = idx >> 10;
        const int k = sgrp * 32 + (lane >> 4) * 8 + j;
        const int col = ct * 16 + (lane & 15);
        const float wv = ldf(s6, k * 128 + col, isf32);
        const short hs = f2bs(wv);
        iiWh[idx] = hs;
        iiWl[idx] = f2bs(wv - bs2f((unsigned short)hs));
        return;
    }
    if (b < 2150) {
        // w1F/w2F from pp_pre_W1 (s0) / pp_pre_W2 (s2), both 64 x 64
        const int local = b - 2118;
        const int isW2 = local >= 16;
        const int idx = (local - (isW2 ? 16 : 0)) * 256 + t;  // < 4096
        const int j = idx & 7, lane = (idx >> 3) & 63, sgrp = (idx >> 9) & 1, ct = idx >> 10;
        const int k = sgrp * 32 + (lane >> 4) * 8 + j;
        const int col = ct * 16 + (lane & 15);
        const void* srcw = isW2 ? s2 : s0;
        const float wv = ldf(srcw, k * 64 + col, isf32);
        const short hs = f2bs(wv);
        short* dh = isW2 ? w2Fh : w1Fh;
        short* dl = isW2 ? w2Fl : w1Fl;
        dh[idx] = hs;
        dl[idx] = f2bs(wv - bs2f((unsigned short)hs));
        return;
    }
    if (b < 2182 || (b >= 2214 && b < 2246)) {
        // K=128 role: pA (pp_post_W1 = s7) or pQ1 (pp1_W1 = s10), both 128 x 64
        const int isQ1 = (b >= 2214);
        const int idx = (b - (isQ1 ? 2214 : 2150)) * 256 + t; // < 8192
        const int j = idx & 7, lane = (idx >> 3) & 63, sgrp = (idx >> 9) & 3, tt = idx >> 11;
        const int k = sgrp * 32 + (lane >> 4) * 8 + j;
        const int col = tt * 16 + (lane & 15);
        const void* srcw = isQ1 ? s10 : s7;
        const float wv = ldf(srcw, k * 64 + col, isf32);
        const short hs = f2bs(wv);
        short* dh = isQ1 ? pQ1h : pAh;
        short* dl = isQ1 ? pQ1l : pAl;
        dh[idx] = hs;
        dl[idx] = f2bs(wv - bs2f((unsigned short)hs));
        return;
    }
    if (b < 2214) {
        // K=64, 64-col role: pB (pp_post_W2 = s8) or pE (eq_pp_W = s9), both 64 x 64
        const int isE = b >= 2198;
        const int idx = (b - (isE ? 2198 : 2182)) * 256 + t;  // < 4096
        const int j = idx & 7, lane = (idx >> 3) & 63, sgrp = (idx >> 9) & 1, ct = idx >> 10;
        const int k = sgrp * 32 + (lane >> 4) * 8 + j;
        const int col = ct * 16 + (lane & 15);
        const void* srcw = isE ? s9 : s8;
        const float wv = ldf(srcw, k * 64 + col, isf32);
        const short hs = f2bs(wv);
        short* dh = isE ? pEh : pBh;
        short* dl = isE ? pEl : pBl;
        dh[idx] = hs;
        dl[idx] = f2bs(wv - bs2f((unsigned short)hs));
        return;
    }
    {
        // K=64, 128-col role: pQ2 from pp1_W2 (s12, 64 x 128)
        const int idx = (b - 2246) * 256 + t;                 // < 8192
        const int j = idx & 7, lane = (idx >> 3) & 63, sgrp = (idx >> 9) & 1, ct = idx >> 10;
        const int k = sgrp * 32 + (lane >> 4) * 8 + j;
        const int col = ct * 16 + (lane & 15);
        const float wv = ldf(s12, k * 128 + col, isf32);
        const short hs = f2bs(wv);
        pQ2h[idx] = hs;
        pQ2l[idx] = f2bs(wv - bs2f((unsigned short)hs));
    }
}

// ---------------- exclusive scan (1 block; fused path only) ----------------
__global__ __launch_bounds__(256) void k_scan(const int* __restrict__ cnt,
                                              int* __restrict__ offs)
{
    __shared__ int part[256];
    __shared__ int base[257];
    const int t = threadIdx.x;
    const int lo = t * 40, hi = (lo + 40 < N_ATOMS) ? lo + 40 : N_ATOMS;
    int s = 0;
    for (int b = lo; b < hi; b++) s += cnt[b];
    part[t] = s;
    __syncthreads();
    if (t == 0) {
        int run = 0;
        for (int i = 0; i < 256; i++) { base[i] = run; run += part[i]; }
        base[256] = run;
    }
    __syncthreads();
    int run = base[t];
    for (int b = lo; b < hi; b++) { offs[b] = run; run += cnt[b]; }
    if (t == 0) offs[N_ATOMS] = base[256];
}

// ---------------- MFMA p1_in + race-free scatter ----------------
// blocks [0,157): p1_in via MFMA (64 atoms/block).
// blocks [157,1407) (fused only): perm[offs[ia]+rank[p]] = p (non-atomic).
__global__ __launch_bounds__(256) void k_prep_scatter(
    const float* __restrict__ wbuf,
    const void* __restrict__ p1, const int* __restrict__ flagp,
    unsigned short* __restrict__ p1h, unsigned short* __restrict__ p1l,
    const int* __restrict__ ind2, const int* __restrict__ offs,
    const int* __restrict__ rank, int* __restrict__ perm,
    const short* __restrict__ w1Fh, const short* __restrict__ w1Fl,
    const short* __restrict__ w2Fh, const short* __restrict__ w2Fl)
{
    __shared__ float hL[64 * 68];
    if (blockIdx.x >= 157) {
        const int p = (blockIdx.x - 157) * 256 + threadIdx.x;
        if (p < N_PAIRS) {
            const int ia = ind2[2 * p];
            perm[offs[ia] + rank[p]] = p;
        }
        return;
    }
    // ---- p1_in via MFMA ----
    const int isf32 = *flagp;
    const int t = threadIdx.x;
    const int lane = t & 63, w = t >> 6, lc = lane & 15, quad = lane >> 4;
    const int B0 = blockIdx.x * 64;

    bf16x8 xh[2], xl[2];
    {
        const int a = B0 + w * 16 + lc;
        const int ar = (a < N_ATOMS) ? a : N_ATOMS - 1;
        #pragma unroll
        for (int s2 = 0; s2 < 2; s2++) {
            const int base = ar * 64 + s2 * 32 + quad * 8;
            #pragma unroll
            for (int j = 0; j < 8; j++) {
                const float x = ldf(p1, base + j, isf32);
                const short hs = f2bs(x);
                xh[s2][j] = hs;
                xl[s2][j] = f2bs(x - bs2f((unsigned short)hs));
            }
        }
    }
    #pragma unroll
    for (int tt = 0; tt < 4; tt++) {
        f32x4 acc = {0.f, 0.f, 0.f, 0.f};
        #pragma unroll
        for (int s2 = 0; s2 < 2; s2++) {
            bf16x8 bh = *(const bf16x8*)&w1Fh[((tt * 2 + s2) * 64 + lane) * 8];
            bf16x8 bl = *(const bf16x8*)&w1Fl[((tt * 2 + s2) * 64 + lane) * 8];
            acc = __builtin_amdgcn_mfma_f32_16x16x32_bf16(xh[s2], bh, acc, 0, 0, 0);
            acc = __builtin_amdgcn_mfma_f32_16x16x32_bf16(xl[s2], bh, acc, 0, 0, 0);
            acc = __builtin_amdgcn_mfma_f32_16x16x32_bf16(xh[s2], bl, acc, 0, 0, 0);
        }
        const int c = tt * 16 + lc;
        const float b1v = wbuf[W_PPREB1 + c];
        #pragma unroll
        for (int r = 0; r < 4; r++) {
            const int m = w * 16 + quad * 4 + r;
            hL[m * 68 + c] = tanh_fast(acc[r] + b1v);
        }
    }
    __syncthreads();
    bf16x8 hh[2], hl[2];
    {
        const int row = w * 16 + lc;
        #pragma unroll
        for (int s2 = 0; s2 < 2; s2++) {
            const float* pr = &hL[row * 68 + s2 * 32 + quad * 8];
            #pragma unroll
            for (int j = 0; j < 8; j++) {
                const float x = pr[j];
                const short hs = f2bs(x);
                hh[s2][j] = hs;
                hl[s2][j] = f2bs(x - bs2f((unsigned short)hs));
            }
        }
    }
    #pragma unroll
    for (int tt = 0; tt < 4; tt++) {
        f32x4 acc = {0.f, 0.f, 0.f, 0.f};
        #pragma unroll
        for (int s2 = 0; s2 < 2; s2++) {
            bf16x8 bh = *(const bf16x8*)&w2Fh[((tt * 2 + s2) * 64 + lane) * 8];
            bf16x8 bl = *(const bf16x8*)&w2Fl[((tt * 2 + s2) * 64 + lane) * 8];
            acc = __builtin_amdgcn_mfma_f32_16x16x32_bf16(hh[s2], bh, acc, 0, 0, 0);
            acc = __builtin_amdgcn_mfma_f32_16x16x32_bf16(hl[s2], bh, acc, 0, 0, 0);
            acc = __builtin_amdgcn_mfma_f32_16x16x32_bf16(hh[s2], bl, acc, 0, 0, 0);
        }
        const int c = tt * 16 + lc;
        const float b2v = wbuf[W_PPREB2 + c];
        #pragma unroll
        for (int r = 0; r < 4; r++) {
            const int m = w * 16 + quad * 4 + r;
            const int a = B0 + m;
            if (a < N_ATOMS) {
                const float f = tanh_fast(acc[r] + b2v);
                const short hs = f2bs(f);
                p1h[a * 64 + c] = (unsigned short)hs;
                p1l[a * 64 + c] = (unsigned short)f2bs(f - bs2f((unsigned short)hs));
            }
        }
    }
}

// ---------------- fused per-pair MFMA + sorted segment-reduce (proven, unchanged) ----------------
__global__ __launch_bounds__(256) void k_pairs_fused(
    const int* __restrict__ ind2, const void* __restrict__ basis,
    const void* __restrict__ d3, const void* __restrict__ fc,
    const int* __restrict__ perm,
    const void* __restrict__ p3,
    const float* __restrict__ wbuf,
    const short* __restrict__ piWB2,
    const short* __restrict__ iiWh, const short* __restrict__ iiWl,
    const unsigned short* __restrict__ p1h, const unsigned short* __restrict__ p1l,
    const int* __restrict__ flagp, const float* __restrict__ vglob,
    float* __restrict__ p1scat, float* __restrict__ p3acc)
{
    // LDS overlay plan (SH = 33280 B; total block LDS ~40.9KB -> 4 blocks/CU):
    //   [0,32768)  Bbuf (merged hi|lo stage)      -- GEMM1 only
    //   [0,17408)  preL (GEMM1->GEMM2 transform)  -- after GEMM1 barrier
    //   [0,33280)  ipL  64 pairs x 130 f32        -- after ah2 barrier
    __shared__ __align__(16) char SH[33280];
    __shared__ float basisL[640];
    __shared__ float biasT[640];
    __shared__ int sIL[65], sJL[64];
    __shared__ float d3L[64][3], t3L[64][3], tbL[64];

    unsigned short* Bbuf = (unsigned short*)SH;
    float* preL = (float*)SH;
    float* ipL  = (float*)SH;

    const int t = threadIdx.x;
    // XCD swizzle: 5000 blocks = 8 XCDs x 625
    const int bid = blockIdx.x;
    const int P0 = ((bid & 7) * 625 + (bid >> 3)) * 64;
    const int isf32 = *flagp;
    const int lane = t & 63;
    const int w = t >> 6;
    const int lc = lane & 15;
    const int quad = lane >> 4;

    if (t < 64) {
        const int p = perm[P0 + t];
        int2 ij = ((const int2*)ind2)[p];
        sIL[t] = ij.x; sJL[t] = ij.y;
        const float vi0 = vglob[ij.x * 3 + 0], vi1 = vglob[ij.x * 3 + 1], vi2 = vglob[ij.x * 3 + 2];
        const float d0 = ldf(d3, 3 * p + 0, isf32);
        const float d1 = ldf(d3, 3 * p + 1, isf32);
        const float d2 = ldf(d3, 3 * p + 2, isf32);
        d3L[t][0] = d0; d3L[t][1] = d1; d3L[t][2] = d2;
        const float proj = vi0 * d0 + vi1 * d1 + vi2 * d2;
        const float w0 = vi0 - proj * d0, w1 = vi1 - proj * d1, w2v = vi2 - proj * d2;
        const float w2 = w0 * w0 + w1 * w1 + w2v * w2v;
        const float g = w2 / (w2 + 1e-4f);
        const float rs = rsqrtf(w2 + 1e-6f);
        t3L[t][0] = w0 * rs * g; t3L[t][1] = w1 * rs * g; t3L[t][2] = w2v * rs * g;
        const float f = ldf(fc, p, isf32);
        tbL[t] = g * f * f;
    }
    if (t == 64) sIL[64] = -1;   // sentinel: forces segment flush at m=63
    // basis gather through perm (40B rows at random offsets; hides under setup)
    for (int e = t; e < 640; e += 256) {
        const int pm = e / 10, col = e - pm * 10;
        basisL[e] = ldf(basis, perm[P0 + pm] * 10 + col, isf32);
    }
    // bias transposed into LDS: biasT[cc*64+c]
    for (int e = t; e < 640; e += 256) biasT[e] = wbuf[W_PIB + (e & 63) * 10 + (e >> 6)];
    __syncthreads();

    // A-frags: row m = lc (pair w*16+lc), k = s*32 + quad*8 + j
    bf16x8 ah[4], al[4];
    {
        const int ia = sIL[w * 16 + lc];
        const int ja = sJL[w * 16 + lc];
        #pragma unroll
        for (int s = 0; s < 4; s++) {
            const int atom = (s < 2) ? ia : ja;
            const int off = atom * 64 + (s & 1) * 32 + quad * 8;
            ah[s] = *(const bf16x8*)(p1h + off);
            al[s] = *(const bf16x8*)(p1l + off);
        }
    }

    // GEMM1: acc = Xh*Wh + Xl*Wh + Xh*Wl  (drop lo*lo)
    float sr[4][4];
    #pragma unroll
    for (int r = 0; r < 4; r++)
        #pragma unroll
        for (int ph = 0; ph < 4; ph++) sr[r][ph] = 0.f;

    for (int cc = 0; cc < 10; cc++) {
        if (cc) __syncthreads();          // prev tile reads done
        {   // stage merged 32KB hi|lo tile (transient regs; no spill)
            const uint4* gsrc = (const uint4*)(piWB2 + cc * 16384);
            uint4* ldst = (uint4*)Bbuf;
            #pragma unroll
            for (int r = 0; r < 8; r++) ldst[r * 256 + t] = gsrc[r * 256 + t];
        }
        __syncthreads();                  // tile staged
        #pragma unroll
        for (int tt = 0; tt < 4; tt++) {
            f32x4 acc = {0.f, 0.f, 0.f, 0.f};
            #pragma unroll
            for (int s = 0; s < 4; s++) {
                const int e = ((tt * 4 + s) * 64 + lane) * 8;
                bf16x8 bh = *(const bf16x8*)&Bbuf[e];
                bf16x8 bl = *(const bf16x8*)&Bbuf[8192 + e];
                acc = __builtin_amdgcn_mfma_f32_16x16x32_bf16(ah[s], bh, acc, 0, 0, 0);
                acc = __builtin_amdgcn_mfma_f32_16x16x32_bf16(al[s], bh, acc, 0, 0, 0);
                acc = __builtin_amdgcn_mfma_f32_16x16x32_bf16(ah[s], bl, acc, 0, 0, 0);
            }
            const float bias = biasT[cc * 64 + tt * 16 + lc];
            #pragma unroll
            for (int r = 0; r < 4; r++) {
                const int m = w * 16 + quad * 4 + r;
                const float h = tanh_fast(acc[r] + bias);
                sr[r][tt] += h * basisL[m * 10 + cc];
            }
        }
    }
    __syncthreads();   // last tile reads done before preL overlay

    // pre -> LDS (C-layout to A-layout transform)
    #pragma unroll
    for (int r = 0; r < 4; r++)
        #pragma unroll
        for (int ph = 0; ph < 4; ph++)
            preL[(w * 16 + quad * 4 + r) * 68 + ph * 16 + lc] = sr[r][ph];
    __syncthreads();

    bf16x8 ah2[2], al2[2];
    {
        const int row = w * 16 + lc;
        #pragma unroll
        for (int s2 = 0; s2 < 2; s2++) {
            const float* pr2 = &preL[row * 68 + s2 * 32 + quad * 8];
            #pragma unroll
            for (int j = 0; j < 8; j++) {
                const float x = pr2[j];
                const short hs = f2bs(x);
                ah2[s2][j] = hs;
                al2[s2][j] = f2bs(x - bs2f((unsigned short)hs));
            }
        }
    }
    __syncthreads();   // preL reads done before ipL overlay writes

    // Phase-B chunk-0 gather: overlaps GEMM2's MFMAs, lands at next barrier
    float pv0[16];
    if (t < 192) {
        #pragma unroll
        for (int u = 0; u < 16; u++) pv0[u] = ldf(p3, sJL[u] * 192 + t, isf32);
    }

    // GEMM2: i_pair -> LDS (stride 130 keeps banks at 2-way = free)
    #pragma unroll
    for (int ct = 0; ct < 8; ct++) {
        f32x4 acc = {0.f, 0.f, 0.f, 0.f};
        #pragma unroll
        for (int s2 = 0; s2 < 2; s2++) {
            bf16x8 bh = *(const bf16x8*)&iiWh[((ct * 2 + s2) * 64 + lane) * 8];
            bf16x8 bl = *(const bf16x8*)&iiWl[((ct * 2 + s2) * 64 + lane) * 8];
            acc = __builtin_amdgcn_mfma_f32_16x16x32_bf16(ah2[s2], bh, acc, 0, 0, 0);
            acc = __builtin_amdgcn_mfma_f32_16x16x32_bf16(al2[s2], bh, acc, 0, 0, 0);
            acc = __builtin_amdgcn_mfma_f32_16x16x32_bf16(ah2[s2], bl, acc, 0, 0, 0);
        }
        const int ch = ct * 16 + lc;
        #pragma unroll
        for (int r = 0; r < 4; r++) {
            const int m = w * 16 + quad * 4 + r;
            ipL[m * 130 + ch] = tanh_fast(acc[r]);
        }
    }
    __syncthreads();   // ipL published (pv0 also complete here)

    if (t < 192) {
        // Phase B (waves 0-2): p3 message segment-sum, one x-component per wave
        const int x = t >> 6, cc2 = t & 63;
        float acc = 0.f;
        #pragma unroll
        for (int blk = 0; blk < 4; blk++) {
            float pv[16];
            if (blk == 0) {
                #pragma unroll
                for (int u = 0; u < 16; u++) pv[u] = pv0[u];
            } else {
                #pragma unroll
                for (int u = 0; u < 16; u++)
                    pv[u] = ldf(p3, sJL[blk * 16 + u] * 192 + t, isf32);
            }
            #pragma unroll
            for (int u = 0; u < 16; u++) {
                const int m = blk * 16 + u;
                const float ipb = ipL[m * 130 + 64 + cc2];
                acc += (pv[u] + d3L[m][x]) * ipb + t3L[m][x] * (ipb * tbL[m]);
                if (sIL[m + 1] != sIL[m]) {
                    atomicAdd(&p3acc[(size_t)sIL[m] * 192 + t], acc);
                    acc = 0.f;
                }
            }
        }
    } else {
        // Phase A (wave 3): p1scat segment-sum, 2 channels per thread
        const int ch0 = t - 192;
        float a0 = 0.f, a1 = 0.f;
        #pragma unroll 8
        for (int m = 0; m < 64; m++) {
            a0 += ipL[m * 130 + ch0];
            a1 += ipL[m * 130 + 64 + ch0];
            if (sIL[m + 1] != sIL[m]) {
                const size_t base = (size_t)sIL[m] * 128;
                atomicAdd(&p1scat[base + ch0], a0);
                atomicAdd(&p1scat[base + 64 + ch0], a1);
                a0 = 0.f; a1 = 0.f;
            }
        }
    }
}

// ---------------- legacy atomic-path per-pair kernel (fallback) ----------------
__global__ __launch_bounds__(256) void k_pairs_atomic(
    const int* __restrict__ ind2, const void* __restrict__ basis,
    const void* __restrict__ d3, const void* __restrict__ fc,
    const void* __restrict__ p3,
    const float* __restrict__ wbuf,
    const short* __restrict__ piWB2,
    const short* __restrict__ iiWh, const short* __restrict__ iiWl,
    const unsigned short* __restrict__ p1h, const unsigned short* __restrict__ p1l,
    const int* __restrict__ flagp, const float* __restrict__ vglob,
    float* __restrict__ outA, float* __restrict__ outB)
{
    __shared__ __align__(16) unsigned short Bbuf[8192];
    __shared__ __align__(16) char SH[17408];
    __shared__ float basisL[640];
    __shared__ int sIL[64], sJL[64];
    __shared__ float d3L[64][3], t3L[64][3], tbL[64];

    float* preL = (float*)SH;
    float* i1bL = (float*)SH;

    const int t = threadIdx.x;
    const int P0 = blockIdx.x * 64;
    const int isf32 = *flagp;
    const int lane = t & 63;
    const int w = t >> 6;
    const int lc = lane & 15;
    const int quad = lane >> 4;

    if (t < 64) {
        int2 ij = ((const int2*)ind2)[P0 + t];
        sIL[t] = ij.x; sJL[t] = ij.y;
    }
    for (int e = t; e < 640; e += 256) basisL[e] = ldf(basis, P0 * 10 + e, isf32);
    __syncthreads();

    bf16x8 ah[4], al[4];
    {
        const int ia = sIL[w * 16 + lc];
        const int ja = sJL[w * 16 + lc];
        #pragma unroll
        for (int s = 0; s < 4; s++) {
            const int atom = (s < 2) ? ia : ja;
            const int off = atom * 64 + (s & 1) * 32 + quad * 8;
            ah[s] = *(const bf16x8*)(p1h + off);
            al[s] = *(const bf16x8*)(p1l + off);
        }
    }

    float sr[4][4];
    #pragma unroll
    for (int r = 0; r < 4; r++)
        #pragma unroll
        for (int ph = 0; ph < 4; ph++) sr[r][ph] = 0.f;

    for (int cc = 0; cc < 10; cc++) {
        f32x4 acc[4];
        #pragma unroll
        for (int tt = 0; tt < 4; tt++) acc[tt] = (f32x4){0.f, 0.f, 0.f, 0.f};

        __syncthreads();
        {
            const uint4* gsrc = (const uint4*)(piWB2 + cc * 16384);
            uint4* ldst = (uint4*)Bbuf;
            #pragma unroll
            for (int r = 0; r < 4; r++) ldst[r * 256 + t] = gsrc[r * 256 + t];
        }
        __syncthreads();
        #pragma unroll
        for (int tt = 0; tt < 4; tt++) {
            #pragma unroll
            for (int s = 0; s < 4; s++) {
                bf16x8 bfr = *(const bf16x8*)&Bbuf[((tt * 4 + s) * 64 + lane) * 8];
                acc[tt] = __builtin_amdgcn_mfma_f32_16x16x32_bf16(ah[s], bfr, acc[tt], 0, 0, 0);
                acc[tt] = __builtin_amdgcn_mfma_f32_16x16x32_bf16(al[s], bfr, acc[tt], 0, 0, 0);
            }
        }
        __syncthreads();
        {
            const uint4* gsrc = (const uint4*)(piWB2 + cc * 16384 + 8192);
            uint4* ldst = (uint4*)Bbuf;
            #pragma unroll
            for (int r = 0; r < 4; r++) ldst[r * 256 + t] = gsrc[r * 256 + t];
        }
        __syncthreads();
        #pragma unroll
        for (int tt = 0; tt < 4; tt++) {
            #pragma unroll
            for (int s = 0; s < 4; s++) {
                bf16x8 bfr = *(const bf16x8*)&Bbuf[((tt * 4 + s) * 64 + lane) * 8];
                acc[tt] = __builtin_amdgcn_mfma_f32_16x16x32_bf16(ah[s], bfr, acc[tt], 0, 0, 0);
            }
            const int c = tt * 16 + lc;
            const float bias = wbuf[W_PIB + c * 10 + cc];
            #pragma unroll
            for (int r = 0; r < 4; r++) {
                const int m = w * 16 + quad * 4 + r;
                const float h = tanh_fast(acc[tt][r] + bias);
                sr[r][tt] += h * basisL[m * 10 + cc];
            }
        }
    }

    #pragma unroll
    for (int r = 0; r < 4; r++)
        #pragma unroll
        for (int ph = 0; ph < 4; ph++)
            preL[(w * 16 + quad * 4 + r) * 68 + ph * 16 + lc] = sr[r][ph];
    __syncthreads();

    bf16x8 ah2[2], al2[2];
    {
        const int row = w * 16 + lc;
        #pragma unroll
        for (int s2 = 0; s2 < 2; s2++) {
            const float* pr2 = &preL[row * 68 + s2 * 32 + quad * 8];
            #pragma unroll
            for (int j = 0; j < 8; j++) {
                const float x = pr2[j];
                const short hs = f2bs(x);
                ah2[s2][j] = hs;
                al2[s2][j] = f2bs(x - bs2f((unsigned short)hs));
            }
        }
    }
    __syncthreads();

    #pragma unroll
    for (int ct = 0; ct < 8; ct++) {
        f32x4 acc = {0.f, 0.f, 0.f, 0.f};
        #pragma unroll
        for (int s2 = 0; s2 < 2; s2++) {
            bf16x8 bh = *(const bf16x8*)&iiWh[((ct * 2 + s2) * 64 + lane) * 8];
            bf16x8 bl = *(const bf16x8*)&iiWl[((ct * 2 + s2) * 64 + lane) * 8];
            acc = __builtin_amdgcn_mfma_f32_16x16x32_bf16(ah2[s2], bh, acc, 0, 0, 0);
            acc = __builtin_amdgcn_mfma_f32_16x16x32_bf16(al2[s2], bh, acc, 0, 0, 0);
            acc = __builtin_amdgcn_mfma_f32_16x16x32_bf16(ah2[s2], bl, acc, 0, 0, 0);
        }
        const int ch = ct * 16 + lc;
        #pragma unroll
        for (int r = 0; r < 4; r++) {
            const int m = w * 16 + quad * 4 + r;
            const float val = tanh_fast(acc[r]);
            atomicAdd(&outA[(size_t)sIL[m] * 128 + ch], val);
            if (ch >= 64) i1bL[m * 64 + (ch - 64)] = val;
        }
    }

    __syncthreads();
    if (t < 64) {
        const int m = t;
        const int ia = sIL[m];
        const float vi0 = vglob[ia * 3 + 0], vi1 = vglob[ia * 3 + 1], vi2 = vglob[ia * 3 + 2];
        const float d0 = ldf(d3, (P0 + m) * 3 + 0, isf32);
        const float d1 = ldf(d3, (P0 + m) * 3 + 1, isf32);
        const float d2 = ldf(d3, (P0 + m) * 3 + 2, isf32);
        d3L[m][0] = d0; d3L[m][1] = d1; d3L[m][2] = d2;
        const float proj = vi0 * d0 + vi1 * d1 + vi2 * d2;
        const float w0 = vi0 - proj * d0, w1 = vi1 - proj * d1, w2v = vi2 - proj * d2;
        const float w2 = w0 * w0 + w1 * w1 + w2v * w2v;
        const float g = w2 / (w2 + 1e-4f);
        const float rs = rsqrtf(w2 + 1e-6f);
        t3L[m][0] = w0 * rs * g; t3L[m][1] = w1 * rs * g; t3L[m][2] = w2v * rs * g;
        const float f = ldf(fc, P0 + m, isf32);
        tbL[m] = g * f * f;
    }
    __syncthreads();
    const int c = lane;
    #pragma unroll 4
    for (int mm = 0; mm < 16; mm++) {
        const int m = w * 16 + mm;
        const float bv = i1bL[m * 64 + c];
        const float coef = bv * tbL[m];
        #pragma unroll
        for (int x = 0; x < 3; x++) {
            const float p3v = ldf(p3, sJL[m] * 192 + x * 64 + c, isf32);
            atomicAdd(&outB[(size_t)sIL[m] * 192 + x * 64 + c],
                      p3v * bv + d3L[m][x] * bv + t3L[m][x] * coef);
        }
    }
}

// ---------------- per-atom epilogue via MFMA (proven, unchanged) ----------------
__global__ __launch_bounds__(256) void k_final_mfma(
    const float* __restrict__ p1scat, const float* __restrict__ p3acc,
    const float* __restrict__ wbuf, const int* __restrict__ flagp,
    const short* __restrict__ pAh, const short* __restrict__ pAl,
    const short* __restrict__ pBh, const short* __restrict__ pBl,
    const short* __restrict__ pEh, const short* __restrict__ pEl,
    const short* __restrict__ pQ1h, const short* __restrict__ pQ1l,
    const short* __restrict__ pQ2h, const short* __restrict__ pQ2l,
    void* __restrict__ out)
{
    __shared__ float hL[64 * 68];
    __shared__ float catL[64 * 132];
    const int isf32 = *flagp;
    const int t = threadIdx.x;
    const int lane = t & 63, w = t >> 6, lc = lane & 15, quad = lane >> 4;
    const int B0 = blockIdx.x * 64;
    const int arow = B0 + w * 16 + lc;
    const int ar = (arow < N_ATOMS) ? arow : N_ATOMS - 1;

    // ---- GEMM 1: hA = tanh(p1scat @ ppW1), K=128 ----
    {
        bf16x8 xh[4], xl[4];
        #pragma unroll
        for (int s = 0; s < 4; s++) {
            const float* src = p1scat + (size_t)ar * 128 + s * 32 + quad * 8;
            #pragma unroll
            for (int j = 0; j < 8; j++) {
                const float x = src[j];
                const short hs = f2bs(x);
                xh[s][j] = hs;
                xl[s][j] = f2bs(x - bs2f((unsigned short)hs));
            }
        }
        #pragma unroll
        for (int tt = 0; tt < 4; tt++) {
            f32x4 acc = {0.f, 0.f, 0.f, 0.f};
            #pragma unroll
            for (int s = 0; s < 4; s++) {
                bf16x8 bh = *(const bf16x8*)&pAh[((tt * 4 + s) * 64 + lane) * 8];
                bf16x8 bl = *(const bf16x8*)&pAl[((tt * 4 + s) * 64 + lane) * 8];
                acc = __builtin_amdgcn_mfma_f32_16x16x32_bf16(xh[s], bh, acc, 0, 0, 0);
                acc = __builtin_amdgcn_mfma_f32_16x16x32_bf16(xl[s], bh, acc, 0, 0, 0);
                acc = __builtin_amdgcn_mfma_f32_16x16x32_bf16(xh[s], bl, acc, 0, 0, 0);
            }
            const int c = tt * 16 + lc;
            #pragma unroll
            for (int r = 0; r < 4; r++)
                hL[(w * 16 + quad * 4 + r) * 68 + c] = tanh_fast(acc[r]);
        }
    }
    __syncthreads();

    // ---- GEMM 2: p1n = tanh(hA @ ppW2) -> catL[:,0:64] ----
    {
        bf16x8 hh[2], hl[2];
        const int row = w * 16 + lc;
        #pragma unroll
        for (int s2 = 0; s2 < 2; s2++) {
            const float* pr = &hL[row * 68 + s2 * 32 + quad * 8];
            #pragma unroll
            for (int j = 0; j < 8; j++) {
                const float x = pr[j];
                const short hs = f2bs(x);
                hh[s2][j] = hs;
                hl[s2][j] = f2bs(x - bs2f((unsigned short)hs));
            }
        }
        #pragma unroll
        for (int tt = 0; tt < 4; tt++) {
            f32x4 acc = {0.f, 0.f, 0.f, 0.f};
            #pragma unroll
            for (int s2 = 0; s2 < 2; s2++) {
                bf16x8 bh = *(const bf16x8*)&pBh[((tt * 2 + s2) * 64 + lane) * 8];
                bf16x8 bl = *(const bf16x8*)&pBl[((tt * 2 + s2) * 64 + lane) * 8];
                acc = __builtin_amdgcn_mfma_f32_16x16x32_bf16(hh[s2], bh, acc, 0, 0, 0);
                acc = __builtin_amdgcn_mfma_f32_16x16x32_bf16(hl[s2], bh, acc, 0, 0, 0);
                acc = __builtin_amdgcn_mfma_f32_16x16x32_bf16(hh[s2], bl, acc, 0, 0, 0);
            }
            const int c = tt * 16 + lc;
            #pragma unroll
            for (int r = 0; r < 4; r++)
                catL[(w * 16 + quad * 4 + r) * 132 + c] = tanh_fast(acc[r]);
        }
    }

    // ---- GEMM 3 (x3): pn[x] = p3acc_x @ eqW (retained in regs) ----
    float pn[3][4][4];
    #pragma unroll
    for (int x = 0; x < 3; x++) {
        bf16x8 ph[2], pl[2];
        #pragma unroll
        for (int s2 = 0; s2 < 2; s2++) {
            const float* src = p3acc + (size_t)ar * 192 + x * 64 + s2 * 32 + quad * 8;
            #pragma unroll
            for (int j = 0; j < 8; j++) {
                const float xv = src[j];
                const short hs = f2bs(xv);
                ph[s2][j] = hs;
                pl[s2][j] = f2bs(xv - bs2f((unsigned short)hs));
            }
        }
        #pragma unroll
        for (int tt = 0; tt < 4; tt++) {
            f32x4 acc = {0.f, 0.f, 0.f, 0.f};
            #pragma unroll
            for (int s2 = 0; s2 < 2; s2++) {
                bf16x8 bh = *(const bf16x8*)&pEh[((tt * 2 + s2) * 64 + lane) * 8];
                bf16x8 bl = *(const bf16x8*)&pEl[((tt * 2 + s2) * 64 + lane) * 8];
                acc = __builtin_amdgcn_mfma_f32_16x16x32_bf16(ph[s2], bh, acc, 0, 0, 0);
                acc = __builtin_amdgcn_mfma_f32_16x16x32_bf16(pl[s2], bh, acc, 0, 0, 0);
                acc = __builtin_amdgcn_mfma_f32_16x16x32_bf16(ph[s2], bl, acc, 0, 0, 0);
            }
            #pragma unroll
            for (int r = 0; r < 4; r++) pn[x][tt][r] = acc[r];
        }
    }
    #pragma unroll
    for (int tt = 0; tt < 4; tt++) {
        const int c = tt * 16 + lc;
        #pragma unroll
        for (int r = 0; r < 4; r++) {
            const float d = pn[0][tt][r] * pn[0][tt][r]
                          + pn[1][tt][r] * pn[1][tt][r]
                          + pn[2][tt][r] * pn[2][tt][r];
            catL[(w * 16 + quad * 4 + r) * 132 + 64 + c] = d;
        }
    }
    __syncthreads();

    // ---- GEMM 4: hB = tanh(cat @ q1W + q1b), K=128 -> hL ----
    {
        bf16x8 ch[4], cl[4];
        const int row = w * 16 + lc;
        #pragma unroll
        for (int s = 0; s < 4; s++) {
            const float* pr = &catL[row * 132 + s * 32 + quad * 8];
            #pragma unroll
            for (int j = 0; j < 8; j++) {
                const float x = pr[j];
                const short hs = f2bs(x);
                ch[s][j] = hs;
                cl[s][j] = f2bs(x - bs2f((unsigned short)hs));
            }
        }
        #pragma unroll
        for (int tt = 0; tt < 4; tt++) {
            f32x4 acc = {0.f, 0.f, 0.f, 0.f};
            #pragma unroll
            for (int s = 0; s < 4; s++) {
                bf16x8 bh = *(const bf16x8*)&pQ1h[((tt * 4 + s) * 64 + lane) * 8];
                bf16x8 bl = *(const bf16x8*)&pQ1l[((tt * 4 + s) * 64 + lane) * 8];
                acc = __builtin_amdgcn_mfma_f32_16x16x32_bf16(ch[s], bh, acc, 0, 0, 0);
                acc = __builtin_amdgcn_mfma_f32_16x16x32_bf16(cl[s], bh, acc, 0, 0, 0);
                acc = __builtin_amdgcn_mfma_f32_16x16x32_bf16(ch[s], bl, acc, 0, 0, 0);
            }
            const int c = tt * 16 + lc;
            const float b1v = wbuf[W_Q1B + c];
            #pragma unroll
            for (int r = 0; r < 4; r++)
                hL[(w * 16 + quad * 4 + r) * 68 + c] = tanh_fast(acc[r] + b1v);
        }
    }
    __syncthreads();

    // ---- GEMM 5: g = tanh(hB @ q2W + q2b), N=128; fused output write ----
    bf16x8 gh[2], gl[2];
    {
        const int row = w * 16 + lc;
        #pragma unroll
        for (int s2 = 0; s2 < 2; s2++) {
            const float* pr = &hL[row * 68 + s2 * 32 + quad * 8];
            #pragma unroll
            for (int j = 0; j < 8; j++) {
                const float x = pr[j];
                const short hs = f2bs(x);
                gh[s2][j] = hs;
                gl[s2][j] = f2bs(x - bs2f((unsigned short)hs));
            }
        }
    }
    float* p1o32 = (float*)out;
    float* p3o32 = p1o32 + 640000;
    __hip_bfloat16* p1o16 = (__hip_bfloat16*)out;
    __hip_bfloat16* p3o16 = p1o16 + 640000;
    #pragma unroll
    for (int ct = 0; ct < 8; ct++) {
        f32x4 acc = {0.f, 0.f, 0.f, 0.f};
        #pragma unroll
        for (int s2 = 0; s2 < 2; s2++) {
            bf16x8 bh = *(const bf16x8*)&pQ2h[((ct * 2 + s2) * 64 + lane) * 8];
            bf16x8 bl = *(const bf16x8*)&pQ2l[((ct * 2 + s2) * 64 + lane) * 8];
            acc = __builtin_amdgcn_mfma_f32_16x16x32_bf16(gh[s2], bh, acc, 0, 0, 0);
            acc = __builtin_amdgcn_mfma_f32_16x16x32_bf16(gl[s2], bh, acc, 0, 0, 0);
            acc = __builtin_amdgcn_mfma_f32_16x16x32_bf16(gh[s2], bl, acc, 0, 0, 0);
        }
        const int col = ct * 16 + lc;
        const float qb = wbuf[W_Q2B + col];
        #pragma unroll
        for (int r = 0; r < 4; r++) {
            const int m = w * 16 + quad * 4 + r;
            const int a = B0 + m;
            if (a >= N_ATOMS) continue;
            const float val = tanh_fast(acc[r] + qb);
            if (ct < 4) {
                if (isf32) p1o32[a * 64 + col] = val;
                else       p1o16[a * 64 + col] = __float2bfloat16(val);
            } else {
                const int c2 = col - 64;
                #pragma unroll
                for (int x = 0; x < 3; x++) {
                    const float pv = pn[x][ct - 4][r] * val;
                    if (isf32) p3o32[a * 192 + x * 64 + c2] = pv;
                    else       p3o16[a * 192 + x * 64 + c2] = __float2bfloat16(pv);
                }
            }
        }
    }
}

extern "C" void kernel_launch(void* const* d_in, const int* in_sizes, int n_in,
                              void* d_out, int out_size, void* d_ws, size_t ws_size,
                              hipStream_t stream)
{
    const int* ind2 = (const int*)d_in[0];
    const void* p1    = d_in[1];
    const void* p3    = d_in[2];
    const void* basis = d_in[3];
    const void* d3    = d_in[4];
    const void* fc    = d_in[5];

    char* W = (char*)d_ws;
    float* wbuf  = (float*)(W + 0);                       // 528128 B
    short* piWB2 = (short*)(W + 528128);                  // 655360 B -> 1183488
    short* iiWh  = (short*)(W + 1183488);                 // 16384 B -> 1199872
    short* iiWl  = (short*)(W + 1199872);                 // 16384 B -> 1216256
    unsigned short* p1h = (unsigned short*)(W + 1216256); // 1280000 B -> 2496256
    unsigned short* p1l = (unsigned short*)(W + 2496256); // 1280000 B -> 3776256
    int* flag = (int*)(W + 3776256);                      // 64 B -> 3776320
    short* w1Fh = (short*)(W + 3776320);                  // 8192 B -> 3784512
    short* w1Fl = (short*)(W + 3784512);                  // 8192 B -> 3792704
    short* w2Fh = (short*)(W + 3792704);                  // 8192 B -> 3800896
    short* w2Fl = (short*)(W + 3800896);                  // 8192 B -> 3809088
    short* pAh  = (short*)(W + 3809088);                  // 16384 B -> 3825472
    short* pAl  = (short*)(W + 3825472);                  // 16384 B -> 3841856
    short* pBh  = (short*)(W + 3841856);                  // 8192 B -> 3850048
    short* pBl  = (short*)(W + 3850048);                  // 8192 B -> 3858240
    short* pEh  = (short*)(W + 3858240);                  // 8192 B -> 3866432
    short* pEl  = (short*)(W + 3866432);                  // 8192 B -> 3874624
    short* pQ1h = (short*)(W + 3874624);                  // 16384 B -> 3891008
    short* pQ1l = (short*)(W + 3891008);                  // 16384 B -> 3907392
    short* pQ2h = (short*)(W + 3907392);                  // 16384 B -> 3923776
    short* pQ2l = (short*)(W + 3923776);                  // 16384 B -> 3940160

    const int fused = (ws_size >= 19500224ULL) ? 1 : 0;

    if (fused) {
        int* offs     = (int*)(W + 3940160);      // 40016 B -> pad 3980224
        int* rank     = (int*)(W + 3980224);      // 1280000 B -> 5260224
        int* perm     = (int*)(W + 5260224);      // 1280000 B -> 6540224
        int* cnt      = (int*)(W + 6540224);      // 40000 B -> 6580224
        float* v      = (float*)(W + 6580224);    // 120000 B -> 6700224
        float* p1scat = (float*)(W + 6700224);    // 5120000 B -> 11820224
        float* p3acc  = (float*)(W + 11820224);   // 7680000 B -> ends 19500224

        // one contiguous zero: cnt + v + p1scat + p3acc
        hipMemsetAsync(cnt, 0, 40000 + 120000 + 5120000 + 7680000, stream);
        k_front<<<2278, 256, 0, stream>>>(d3, fc, flag, ind2, cnt, v, rank,
            d_in[6], d_in[7], d_in[8], d_in[9], d_in[10], d_in[11], d_in[12],
            d_in[13], d_in[14], d_in[15], d_in[16], d_in[17], d_in[18], d_in[19],
            wbuf, piWB2, iiWh, iiWl, w1Fh, w1Fl, w2Fh, w2Fl,
            pAh, pAl, pBh, pBl, pEh, pEl, pQ1h, pQ1l, pQ2h, pQ2l);
        k_scan<<<1, 256, 0, stream>>>(cnt, offs);
        k_prep_scatter<<<1407, 256, 0, stream>>>(wbuf, p1, flag, p1h, p1l,
                                                 ind2, offs, rank, perm,
                                                 w1Fh, w1Fl, w2Fh, w2Fl);
        k_pairs_fused<<<5000, 256, 0, stream>>>(ind2, basis, d3, fc, perm, p3,
                                                wbuf, piWB2, iiWh, iiWl,
                                                p1h, p1l, flag, v, p1scat, p3acc);
        k_final_mfma<<<157, 256, 0, stream>>>(p1scat, p3acc, wbuf, flag,
                                              pAh, pAl, pBh, pBl, pEh, pEl,
                                              pQ1h, pQ1l, pQ2h, pQ2l, d_out);
    } else {
        int* cnt      = (int*)(W + 3940160);      // 40000 B -> 3980160
        float* v      = (float*)(W + 3980160);    // 120000 B -> 4100160
        float* p1scat = (float*)(W + 4100160);    // 5120000 B -> 9220160
        float* p3acc  = (float*)(W + 9220160);    // 7680000 B -> 16900160
        int* rank     = (int*)(W + 16900160);     // 1280000 B -> ends 18180160

        hipMemsetAsync(cnt, 0, 40000 + 120000 + 5120000 + 7680000, stream);
        k_front<<<2278, 256, 0, stream>>>(d3, fc, flag, ind2, cnt, v, rank,
            d_in[6], d_in[7], d_in[8], d_in[9], d_in[10], d_in[11], d_in[12],
            d_in[13], d_in[14], d_in[15], d_in[16], d_in[17], d_in[18], d_in[19],
            wbuf, piWB2, iiWh, iiWl, w1Fh, w1Fl, w2Fh, w2Fl,
            pAh, pAl, pBh, pBl, pEh, pEl, pQ1h, pQ1l, pQ2h, pQ2l);
        k_prep_scatter<<<157, 256, 0, stream>>>(wbuf, p1, flag, p1h, p1l,
                                                nullptr, nullptr, nullptr, nullptr,
                                                w1Fh, w1Fl, w2Fh, w2Fl);
        k_pairs_atomic<<<5000, 256, 0, stream>>>(ind2, basis, d3, fc, p3,
                                                 wbuf, piWB2, iiWh, iiWl,
                                                 p1h, p1l, flag, v,
                                                 p1scat, p3acc);
        k_final_mfma<<<157, 256, 0, stream>>>(p1scat, p3acc, wbuf, flag,
                                              pAh, pAl, pBh, pBl, pEh, pEl,
                                              pQ1h, pQ1l, pQ2h, pQ2l, d_out);
    }
}